// Round 9
// baseline (245.188 us; speedup 1.0000x reference)
//
#include <hip/hip_runtime.h>
#include <hip/hip_bf16.h>

// Problem constants
constexpr int kB   = 2;
constexpr int kS   = 2048;
constexpr int kD   = 1024;
constexpr int kH   = 16;
constexpr int kDh  = 64;
constexpr int kBS  = kB * kS;          // 4096 rows

typedef __attribute__((ext_vector_type(8))) short short8;   // 8 bf16 = 4 VGPRs
typedef __attribute__((ext_vector_type(4))) float floatx4;  // MFMA acc 16x16
typedef __attribute__((ext_vector_type(16))) float floatx16; // MFMA acc 32x32

__device__ inline unsigned short f2b(float f) {
    __hip_bfloat16 h = __float2bfloat16(f);
    return *reinterpret_cast<unsigned short*>(&h);
}

__device__ inline float b2f(unsigned short u) {
    union { unsigned u; float f; } cv;
    cv.u = (unsigned)u << 16;
    return cv.f;
}

__device__ inline floatx4 mfma16(short8 a, short8 b, floatx4 c) {
    return __builtin_amdgcn_mfma_f32_16x16x32_bf16(a, b, c, 0, 0, 0);
}

__device__ inline floatx16 mfma32(short8 a, short8 b, floatx16 c) {
    return __builtin_amdgcn_mfma_f32_32x32x16_bf16(a, b, c, 0, 0, 0);
}

// truncating pack of two f32 -> one u32 of 2 bf16 (lo = a, hi = b).
// Truncating is part of the round-3 verified arithmetic — do not change
// (absmax 0.03125 depends on reproducing it bit-exactly).
__device__ inline unsigned packbf(float a, float b) {
    union { float f; unsigned u; } x, y;
    x.f = a; y.f = b;
    return (x.u >> 16) | (y.u & 0xffff0000u);
}

// async global->LDS, 16B per lane; LDS dest = wave-uniform base + lane*16
__device__ inline void gload16(const unsigned short* g, unsigned short* l) {
    __builtin_amdgcn_global_load_lds(
        (const __attribute__((address_space(1))) void*)g,
        (__attribute__((address_space(3))) void*)l, 16, 0, 0);
}

// ---------------------------------------------------------------------------
// K0: fp32 -> bf16 conversion of x (4M elems) and the 4 weights (4 x 1M elems)
// ---------------------------------------------------------------------------
__global__ void convert_kernel(const float* __restrict__ x,
                               const float* __restrict__ wq, const float* __restrict__ wk,
                               const float* __restrict__ wv, const float* __restrict__ wo,
                               unsigned short* __restrict__ xb, unsigned short* __restrict__ wb) {
    int gid = blockIdx.x * blockDim.x + threadIdx.x;
    long i4 = (long)gid * 4;
    const float* src;
    unsigned short* dst;
    long off;
    if (i4 < (long)kBS * kD) {
        src = x; dst = xb; off = i4;
    } else {
        long w = i4 - (long)kBS * kD;
        int sel = (int)(w >> 20);
        off = w & 1048575;
        src = (sel == 0) ? wq : (sel == 1) ? wk : (sel == 2) ? wv : wo;
        dst = wb + (long)sel * 1048576;
    }
    float4 v = *(const float4*)(src + off);
    ushort4 o;
    o.x = f2b(v.x); o.y = f2b(v.y); o.z = f2b(v.z); o.w = f2b(v.w);
    *(ushort4*)(dst + off) = o;
}

// ---------------------------------------------------------------------------
// K1: NT GEMM  C[M,N] = A[M,K] @ B[N,K]^T   (bf16 in, fp32 accum)
// BK=64: 32 MFMAs per barrier-pair. Staging via global_load_lds w=16 with
// 8-chunk XOR swizzle; 32 KB LDS, 2 blocks/CU.
// MODE 0: bf16 C; z==0 (Q) scaled by 0.125*log2(e) (exp2 domain).
// MODE 1: fp32 C + residual.
// ---------------------------------------------------------------------------
template <int MODE>
__launch_bounds__(256, 2)
__global__ void gemm_nt(const unsigned short* __restrict__ A,
                        const unsigned short* __restrict__ Bw,
                        void* __restrict__ Cout,
                        const float* __restrict__ resid,
                        int M, int N, int K) {
    __shared__ __align__(16) unsigned short As[128 * 64];
    __shared__ __align__(16) unsigned short Bs[128 * 64];

    const int z  = blockIdx.z;
    const unsigned short* Bp = Bw + (size_t)z * N * K;
    const int m0 = blockIdx.y * 128, n0 = blockIdx.x * 128;
    const int tid  = threadIdx.x;
    const int lane = tid & 63, wv = tid >> 6;
    const int wm = wv >> 1, wn = wv & 1;
    const int quad = lane >> 4, l16 = lane & 15;

    floatx4 acc[4][4] = {};

    const int r0 = lane >> 3;
    const int jc = ((lane & 7) ^ r0) * 8;
    const unsigned short* Ag[4];
    const unsigned short* Bg[4];
    unsigned short* Asd[4];
    unsigned short* Bsd[4];
#pragma unroll
    for (int seg = 0; seg < 4; seg++) {
        const int row = seg * 32 + wv * 8 + r0;        // 0..127
        Ag[seg] = A  + (size_t)(m0 + row) * K + jc;    // + k0 per iter
        Bg[seg] = Bp + (size_t)(n0 + row) * K + jc;
        Asd[seg] = As + (seg * 32 + wv * 8) * 64;      // wave-uniform
        Bsd[seg] = Bs + (seg * 32 + wv * 8) * 64;
    }

    const int pk0 = (quad ^ (l16 & 7)) * 8;
    const int pk1 = ((4 + quad) ^ (l16 & 7)) * 8;

    for (int k0 = 0; k0 < K; k0 += 64) {
        __syncthreads();
#pragma unroll
        for (int seg = 0; seg < 4; seg++) {
            gload16(Ag[seg] + k0, Asd[seg]);
            gload16(Bg[seg] + k0, Bsd[seg]);
        }
        __syncthreads();

#pragma unroll
        for (int h = 0; h < 2; h++) {
            const int pk = h ? pk1 : pk0;
            short8 af[4], bf[4];
#pragma unroll
            for (int i = 0; i < 4; i++)
                af[i] = *(const short8*)(As + (wm * 64 + i * 16 + l16) * 64 + pk);
#pragma unroll
            for (int j = 0; j < 4; j++)
                bf[j] = *(const short8*)(Bs + (wn * 64 + j * 16 + l16) * 64 + pk);
#pragma unroll
            for (int i = 0; i < 4; i++)
#pragma unroll
                for (int j = 0; j < 4; j++)
                    acc[i][j] = mfma16(af[i], bf[j], acc[i][j]);
        }
    }

#pragma unroll
    for (int i = 0; i < 4; i++)
#pragma unroll
        for (int j = 0; j < 4; j++) {
            const int row = m0 + wm * 64 + i * 16 + quad * 4;
            const int col = n0 + wn * 64 + j * 16 + l16;
#pragma unroll
            for (int r = 0; r < 4; r++) {
                float v = acc[i][j][r];
                if (MODE == 0) {
                    if (z == 0) v *= 0.18033688f;   // 0.125 * log2(e)
                    ((unsigned short*)Cout)[(size_t)z * M * N + (size_t)(row + r) * N + col] = f2b(v);
                } else {
                    size_t idx = (size_t)(row + r) * N + col;
                    ((float*)Cout)[idx] = v + resid[idx];
                }
            }
        }
}

// ---------------------------------------------------------------------------
// K2: FUSED column-softmax denominators + scaled V^T — round 15: 4 waves
// share one Q staging tile. Block = 256 threads (4 waves x 32 keys = 128
// keys); grid 512, XCD-swizzled.
// Phase 1: invl[k] = 1/sum_q exp2(s[q,k]) (K-stationary).
// Phase 2: VT[bh][d][k] = V[b][k][h*64+d] * invl[k], two 64-key groups.
// ---------------------------------------------------------------------------
__launch_bounds__(256, 4)
__global__ void stats_vt_kernel(const unsigned short* __restrict__ Qb,
                                const unsigned short* __restrict__ Kb,
                                const unsigned short* __restrict__ Vb,
                                unsigned short* __restrict__ VT) {
    __shared__ __align__(16) unsigned short Qs[64 * 68];  // staging (64) / transpose tile (65)
    __shared__ float s_inv[128];

    const int id = blockIdx.x;                       // 0..511
    const int bh = (id & 7) + 8 * ((id >> 3) & 3);   // XCD-grouped
    const int keyblk = id >> 5;                      // 0..15
    const int b = bh >> 4, h = bh & 15;
    const int tid = threadIdx.x, lane = tid & 63, w = tid >> 6;   // w = 0..3
    const int quad = lane >> 4, l16 = lane & 15;
    const int keybase = keyblk * 128 + w * 32;

    // A-frags: K rows (2 key-tiles x 2 dh-halves), held in regs
    short8 ak[2][2];
#pragma unroll
    for (int s = 0; s < 2; s++) {
        const unsigned short* Krow = Kb + (size_t)(b * kS + keybase + s * 16 + l16) * kD + h * kDh;
        ak[s][0] = *(const short8*)(Krow + quad * 8);
        ak[s][1] = *(const short8*)(Krow + 32 + quad * 8);
    }

    // staging: wave w covers rows w*16 .. w*16+15 (2 segs of 8 rows);
    // lane covers row seg*8 + (lane>>3), logical 16B chunk (lane&7)^r0
    const int r0 = lane >> 3;
    const int jc = ((lane & 7) ^ r0) * 8;
    const unsigned short* Qg[2];
    unsigned short* Ql[2];
#pragma unroll
    for (int seg = 0; seg < 2; seg++) {
        const int row = w * 16 + seg * 8 + r0;              // 0..63
        Qg[seg] = Qb + (size_t)(b * kS + row) * kD + h * kDh + jc;   // + q0*kD per chunk
        Ql[seg] = Qs + (w * 16 + seg * 8) * 64;             // wave-uniform
    }

    const int pk0 = (quad ^ (l16 & 7)) * 8;
    const int pk1 = ((4 + quad) ^ (l16 & 7)) * 8;

    float lacc[2][4] = {};

    for (int q0 = 0; q0 < kS; q0 += 64) {
        __syncthreads();
#pragma unroll
        for (int seg = 0; seg < 2; seg++)
            gload16(Qg[seg] + (size_t)q0 * kD, Ql[seg]);
        __syncthreads();

#pragma unroll
        for (int c = 0; c < 4; c++) {
            const unsigned short* row = Qs + (c * 16 + l16) * 64;
            short8 bq0 = *(const short8*)(row + pk0);
            short8 bq1 = *(const short8*)(row + pk1);
#pragma unroll
            for (int s = 0; s < 2; s++) {
                floatx4 t = {0.f, 0.f, 0.f, 0.f};
                t = mfma16(ak[s][0], bq0, t);
                t = mfma16(ak[s][1], bq1, t);
#pragma unroll
                for (int r = 0; r < 4; r++)
                    lacc[s][r] += exp2f(t[r]);
            }
        }
    }

    // reduce across the 16 l16 lanes within each quad
#pragma unroll
    for (int off = 1; off <= 8; off <<= 1)
#pragma unroll
        for (int s = 0; s < 2; s++)
#pragma unroll
            for (int r = 0; r < 4; r++)
                lacc[s][r] += __shfl_xor(lacc[s][r], off, 64);

    __syncthreads();   // Qs reads done before tile reuse; also orders s_inv
    if (l16 == 0) {
#pragma unroll
        for (int s = 0; s < 2; s++)
#pragma unroll
            for (int r = 0; r < 4; r++)
                s_inv[w * 32 + s * 16 + quad * 4 + r] = 1.0f / lacc[s][r];
    }
    __syncthreads();

    // Phase 2: scaled V^T for this block's 128 keys, two 64-key groups.
    unsigned short* tile = Qs;   // reuse, stride 65
#pragma unroll
    for (int g = 0; g < 2; g++) {
        const int kr = tid >> 2, dc = (tid & 3) * 16;
        {
            const float iv = s_inv[g * 64 + kr];
            const unsigned short* src =
                Vb + (size_t)(b * kS + keyblk * 128 + g * 64 + kr) * kD + h * kDh + dc;
            unsigned short vs[16];
            *(uint4*)(vs)     = *(const uint4*)(src);
            *(uint4*)(vs + 8) = *(const uint4*)(src + 8);
#pragma unroll
            for (int i = 0; i < 16; i++)
                tile[kr * 65 + dc + i] = f2b(b2f(vs[i]) * iv);
        }
        __syncthreads();
        {
            const int d = tid >> 2, kc = (tid & 3) * 16;
            unsigned short os[16];
#pragma unroll
            for (int j = 0; j < 16; j++) os[j] = tile[(kc + j) * 65 + d];
            unsigned short* dst =
                VT + (size_t)bh * kDh * kS + (size_t)d * kS + keyblk * 128 + g * 64 + kc;
            *(uint4*)(dst)     = *(uint4*)(os);
            *(uint4*)(dst + 8) = *(uint4*)(os + 8);
        }
        __syncthreads();   // tile reuse for next group
    }
}

// ---------------------------------------------------------------------------
// K3: ctx = exp2(S) @ VT^T — round 21 resubmit (round-8 GPU acquisition
// timed out; change untested): tile-pair interleave.
// Round-7 post-mortem: issue-early dbuf neutral (barrier drain NOT the
// stall); 5000 cy/CU-iter with no pipe >55% and occupancy grid-capped at
// 2 blocks/CU (q-parallelism exhausted at 2048 waves) -> latency-bound on
// the per-wave serial chain QK^T -> exp2 -> pack -> PV.
// Fix: process TWO 64-key tiles per barrier-pair. Stage both (32 KB, same
// as r7), one barrier, then the two round-3-verbatim compute bodies
// back-to-back with NO barrier between: tile1's ds_read/QK^T overlap
// tile0's exp2/pack/PV (MFMA || VALU || LDS across tiles). Barriers 64->32.
// Numerics: per-output accumulation order UNCHANGED (k then k+64, same
// per-wave data/order) -> absmax must be exactly 0.03125 (round-4 lesson:
// any reordering risks the tight threshold).
// ---------------------------------------------------------------------------
__launch_bounds__(256, 2)
__global__ void ctx_kernel(const unsigned short* __restrict__ Qb,
                           const unsigned short* __restrict__ Kb,
                           const unsigned short* __restrict__ VT,
                           unsigned short* __restrict__ Ctx) {
    // [tile][0] = K tile, [tile][1] = VT tile; 32 KB total.
    __shared__ __align__(16) unsigned short Sh[2][2][64 * 64];

    const int id = blockIdx.x;                       // 0..511
    const int bh = (id & 7) + 8 * ((id >> 3) & 3);   // XCD-grouped
    const int qblk = id >> 5;                        // 0..15
    const int b = bh >> 4, h = bh & 15;
    const int tid = threadIdx.x, lane = tid & 63, w = tid >> 6;   // w = 0..3
    const int l32 = lane & 31, hi = lane >> 5;
    const int qbase = qblk * 128 + w * 32;           // 32 q per wave

    // Q-frags (B-operand of QK^T), 4 dh-ksteps: lane: q=l32, dh=kq*16+hi*8
    short8 aq[4];
    {
        const unsigned short* Qrow =
            Qb + (size_t)(b * kS + qbase + l32) * kD + h * kDh + hi * 8;
#pragma unroll
        for (int kq = 0; kq < 4; kq++)
            aq[kq] = *(const short8*)(Qrow + kq * 16);
    }
    floatx16 acc[2] = {};   // PV acc: d-tiles t=0,1 (rows=q via regs, col=lane&31=d)

    const unsigned short* Kbase = Kb + (size_t)(b * kS) * kD + h * kDh;
    const unsigned short* VTb   = VT + (size_t)bh * kDh * kS;

    // staging: 4 waves cover 64 rows, XOR-chunk source (linear LDS dest)
    const int r0 = lane >> 3;
    const int jc = ((lane & 7) ^ r0) * 8;
    const unsigned short* Kg[2];
    const unsigned short* Vg[2];
    int loff[2];
#pragma unroll
    for (int seg = 0; seg < 2; seg++) {
        const int row = w * 16 + seg * 8 + r0;         // 0..63
        Kg[seg] = Kbase + (size_t)row * kD + jc;       // + k0*kD per chunk
        Vg[seg] = VTb + (size_t)row * kS + jc;         // + k0 per chunk
        loff[seg] = (w * 16 + seg * 8) * 64;           // wave-uniform
    }

    const int x7 = l32 & 7;    // row&7 for the chunk swizzle

    for (int k0 = 0; k0 < kS; k0 += 128) {
        // stage tile k0 into Sh[0], tile k0+64 into Sh[1]
#pragma unroll
        for (int seg = 0; seg < 2; seg++) {
            gload16(Kg[seg] + (size_t)k0 * kD,        &Sh[0][0][loff[seg]]);
            gload16(Vg[seg] + k0,                     &Sh[0][1][loff[seg]]);
            gload16(Kg[seg] + (size_t)(k0 + 64) * kD, &Sh[1][0][loff[seg]]);
            gload16(Vg[seg] + (k0 + 64),              &Sh[1][1][loff[seg]]);
        }
        __syncthreads();   // implicit vmcnt(0): both tiles landed

        // two round-3-verbatim compute bodies, no barrier between ->
        // compiler can interleave tile1's ds_read/QK^T with tile0's
        // exp2/pack/PV. Accumulation order preserved (tb=0 then tb=1).
#pragma unroll
        for (int tb = 0; tb < 2; tb++) {
            const unsigned short* Ks  = Sh[tb][0];
            const unsigned short* VTs = Sh[tb][1];

            // QK^T: sc[s] = K-tile(s) x Q -> D[key][q], col=lane&31=q,
            // key = (r&3) + 8*(r>>2) + 4*hi (+32s)
            floatx16 sc[2];
#pragma unroll
            for (int s = 0; s < 2; s++) {
                const unsigned short* arow = Ks + (s * 32 + l32) * 64;
                floatx16 t = {0.f,0.f,0.f,0.f,0.f,0.f,0.f,0.f,
                              0.f,0.f,0.f,0.f,0.f,0.f,0.f,0.f};
#pragma unroll
                for (int kq = 0; kq < 4; kq++) {
                    short8 af = *(const short8*)(arow + ((2 * kq + hi) ^ x7) * 8);
                    t = mfma32(af, aq[kq], t);
                }
                sc[s] = t;
            }

            // P build fully in-register: exp2 -> truncating bf16 pack ->
            // permlane32_swap. pa[kk] = A-frag (q=l32, keys kk*16+hi*8..+8).
            short8 pa[4];
#pragma unroll
            for (int s = 0; s < 2; s++) {
                float e[16];
#pragma unroll
                for (int r = 0; r < 16; r++) e[r] = exp2f(sc[s][r]);
                unsigned p0 = packbf(e[0],  e[1]),  p1 = packbf(e[2],  e[3]);
                unsigned p2 = packbf(e[4],  e[5]),  p3 = packbf(e[6],  e[7]);
                unsigned p4 = packbf(e[8],  e[9]),  p5 = packbf(e[10], e[11]);
                unsigned p6 = packbf(e[12], e[13]), p7 = packbf(e[14], e[15]);
                asm volatile("v_permlane32_swap_b32 %0, %1" : "+v"(p0), "+v"(p2));
                asm volatile("v_permlane32_swap_b32 %0, %1" : "+v"(p1), "+v"(p3));
                asm volatile("v_permlane32_swap_b32 %0, %1" : "+v"(p4), "+v"(p6));
                asm volatile("v_permlane32_swap_b32 %0, %1" : "+v"(p5), "+v"(p7));
                union { unsigned u[4]; short8 v; } f0, f1;
                f0.u[0] = p0; f0.u[1] = p1; f0.u[2] = p2; f0.u[3] = p3;
                f1.u[0] = p4; f1.u[1] = p5; f1.u[2] = p6; f1.u[3] = p7;
                pa[2 * s]     = f0.v;
                pa[2 * s + 1] = f1.v;
            }

            // PV: acc[t] += P x VT-tile(t) -> D[q][d]
#pragma unroll
            for (int t = 0; t < 2; t++) {
                const unsigned short* brow = VTs + (t * 32 + l32) * 64;
#pragma unroll
                for (int kk = 0; kk < 4; kk++) {
                    short8 bv = *(const short8*)(brow + ((2 * kk + hi) ^ x7) * 8);
                    acc[t] = mfma32(pa[kk], bv, acc[t]);
                }
            }
        }

        __syncthreads();   // all reads done before next stage overwrites
    }

    // D layout: col=lane&31 = d_local (within tile t), row q = (r&3)+8*(r>>2)+4*hi
#pragma unroll
    for (int t = 0; t < 2; t++)
#pragma unroll
        for (int rg = 0; rg < 4; rg++)
#pragma unroll
            for (int j = 0; j < 4; j++) {
                const int q = qbase + rg * 8 + hi * 4 + j;
                const int d = h * kDh + t * 32 + l32;
                Ctx[(size_t)(b * kS + q) * kD + d] = f2b(acc[t][rg * 4 + j]);
            }
}

// ---------------------------------------------------------------------------
// K4: row LayerNorm
// ---------------------------------------------------------------------------
__global__ void ln_kernel(const float* __restrict__ R, const float* __restrict__ gamma,
                          const float* __restrict__ beta, float* __restrict__ out) {
    const int row = blockIdx.x;
    const int tid = threadIdx.x;
    const float4 v = ((const float4*)(R + (size_t)row * kD))[tid];
    float s  = v.x + v.y + v.z + v.w;
    float ss = v.x * v.x + v.y * v.y + v.z * v.z + v.w * v.w;
#pragma unroll
    for (int off = 32; off > 0; off >>= 1) {
        s  += __shfl_down(s, off, 64);
        ss += __shfl_down(ss, off, 64);
    }
    __shared__ float ws_s[4], ws_ss[4];
    __shared__ float mu_sh, inv_sh;
    const int lane = tid & 63, w = tid >> 6;
    if (lane == 0) { ws_s[w] = s; ws_ss[w] = ss; }
    __syncthreads();
    if (tid == 0) {
        float S1 = ws_s[0] + ws_s[1] + ws_s[2] + ws_s[3];
        float S2 = ws_ss[0] + ws_ss[1] + ws_ss[2] + ws_ss[3];
        float mu = S1 * (1.0f / kD);
        float var = S2 * (1.0f / kD) - mu * mu;
        mu_sh = mu;
        inv_sh = rsqrtf(var + 1e-5f);
    }
    __syncthreads();
    const float mu = mu_sh, inv = inv_sh;
    const float4 g  = ((const float4*)gamma)[tid];
    const float4 bb = ((const float4*)beta)[tid];
    float4 o;
    o.x = (v.x - mu) * inv * g.x + bb.x;
    o.y = (v.y - mu) * inv * g.y + bb.y;
    o.z = (v.z - mu) * inv * g.z + bb.z;
    o.w = (v.w - mu) * inv * g.w + bb.w;
    ((float4*)(out + (size_t)row * kD))[tid] = o;
}

// ---------------------------------------------------------------------------
// Workspace layout (64 MB peak, aliasing is stream-ordered-safe):
//   [0,   8MB)  Xb bf16
//   [8,  16MB)  Wb bf16 wq|wk|wv|wo
//   [16, 40MB)  QKV bf16 Q|K|V  (Q pre-scaled by 0.125*log2e)
//   [40, 48MB)  Ctx bf16
//   [48, 64MB)  VT bf16 [32][64][2048]; ALIASES R (written strictly later)
// ---------------------------------------------------------------------------
extern "C" void kernel_launch(void* const* d_in, const int* in_sizes, int n_in,
                              void* d_out, int out_size, void* d_ws, size_t ws_size,
                              hipStream_t stream) {
    const float* x     = (const float*)d_in[0];
    const float* wq    = (const float*)d_in[1];
    const float* wk    = (const float*)d_in[2];
    const float* wv    = (const float*)d_in[3];
    const float* wo    = (const float*)d_in[4];
    const float* gamma = (const float*)d_in[5];
    const float* beta  = (const float*)d_in[6];
    float* out = (float*)d_out;

    char* ws = (char*)d_ws;
    unsigned short* Xb  = (unsigned short*)(ws);
    unsigned short* Wb  = (unsigned short*)(ws + (8u  << 20));
    unsigned short* QKV = (unsigned short*)(ws + (16u << 20));
    unsigned short* Qb  = QKV;
    unsigned short* Kb  = QKV + (size_t)kBS * kD;
    unsigned short* Vb  = QKV + (size_t)2 * kBS * kD;
    unsigned short* Ctx = (unsigned short*)(ws + (40u << 20));
    unsigned short* VT  = (unsigned short*)(ws + (48u << 20));
    float* R            = (float*)(ws + (48u << 20));  // aliases VT

    convert_kernel<<<8192, 256, 0, stream>>>(x, wq, wk, wv, wo, Xb, Wb);

    gemm_nt<0><<<dim3(kD / 128, kBS / 128, 3), 256, 0, stream>>>(
        Xb, Wb, QKV, nullptr, kBS, kD, kD);

    stats_vt_kernel<<<512, 256, 0, stream>>>(Qb, Kb, Vb, VT);

    ctx_kernel<<<512, 256, 0, stream>>>(Qb, Kb, VT, Ctx);

    gemm_nt<1><<<dim3(kD / 128, kBS / 128, 1), 256, 0, stream>>>(
        Ctx, Wb + (size_t)3 * kD * kD, R, x, kBS, kD, kD);

    ln_kernel<<<kBS, 256, 0, stream>>>(R, gamma, beta, out);
}

// Round 10
// 239.143 us; speedup vs baseline: 1.0253x; 1.0253x over previous
//
#include <hip/hip_runtime.h>
#include <hip/hip_bf16.h>

// Problem constants
constexpr int kB   = 2;
constexpr int kS   = 2048;
constexpr int kD   = 1024;
constexpr int kH   = 16;
constexpr int kDh  = 64;
constexpr int kBS  = kB * kS;          // 4096 rows

typedef __attribute__((ext_vector_type(8))) short short8;   // 8 bf16 = 4 VGPRs
typedef __attribute__((ext_vector_type(4))) float floatx4;  // MFMA acc 16x16
typedef __attribute__((ext_vector_type(16))) float floatx16; // MFMA acc 32x32

__device__ inline unsigned short f2b(float f) {
    __hip_bfloat16 h = __float2bfloat16(f);
    return *reinterpret_cast<unsigned short*>(&h);
}

__device__ inline float b2f(unsigned short u) {
    union { unsigned u; float f; } cv;
    cv.u = (unsigned)u << 16;
    return cv.f;
}

__device__ inline floatx4 mfma16(short8 a, short8 b, floatx4 c) {
    return __builtin_amdgcn_mfma_f32_16x16x32_bf16(a, b, c, 0, 0, 0);
}

__device__ inline floatx16 mfma32(short8 a, short8 b, floatx16 c) {
    return __builtin_amdgcn_mfma_f32_32x32x16_bf16(a, b, c, 0, 0, 0);
}

// truncating pack of two f32 -> one u32 of 2 bf16 (lo = a, hi = b).
// Truncating is part of the round-3 verified arithmetic — do not change
// (absmax 0.03125 depends on reproducing it bit-exactly).
__device__ inline unsigned packbf(float a, float b) {
    union { float f; unsigned u; } x, y;
    x.f = a; y.f = b;
    return (x.u >> 16) | (y.u & 0xffff0000u);
}

// async global->LDS, 16B per lane; LDS dest = wave-uniform base + lane*16
__device__ inline void gload16(const unsigned short* g, unsigned short* l) {
    __builtin_amdgcn_global_load_lds(
        (const __attribute__((address_space(1))) void*)g,
        (__attribute__((address_space(3))) void*)l, 16, 0, 0);
}

// ---------------------------------------------------------------------------
// K0: fp32 -> bf16 conversion of x (4M elems) and the 4 weights (4 x 1M elems)
// ---------------------------------------------------------------------------
__global__ void convert_kernel(const float* __restrict__ x,
                               const float* __restrict__ wq, const float* __restrict__ wk,
                               const float* __restrict__ wv, const float* __restrict__ wo,
                               unsigned short* __restrict__ xb, unsigned short* __restrict__ wb) {
    int gid = blockIdx.x * blockDim.x + threadIdx.x;
    long i4 = (long)gid * 4;
    const float* src;
    unsigned short* dst;
    long off;
    if (i4 < (long)kBS * kD) {
        src = x; dst = xb; off = i4;
    } else {
        long w = i4 - (long)kBS * kD;
        int sel = (int)(w >> 20);
        off = w & 1048575;
        src = (sel == 0) ? wq : (sel == 1) ? wk : (sel == 2) ? wv : wo;
        dst = wb + (long)sel * 1048576;
    }
    float4 v = *(const float4*)(src + off);
    ushort4 o;
    o.x = f2b(v.x); o.y = f2b(v.y); o.z = f2b(v.z); o.w = f2b(v.w);
    *(ushort4*)(dst + off) = o;
}

// ---------------------------------------------------------------------------
// K1: NT GEMM  C[M,N] = A[M,K] @ B[N,K]^T   (bf16 in, fp32 accum)
// BK=64: 32 MFMAs per barrier-pair. Staging via global_load_lds w=16 with
// 8-chunk XOR swizzle; 32 KB LDS.
// Round 10: __launch_bounds__ 2 -> 3 waves/EU so MODE-0's 768 blocks fit
// in ONE resident generation (3 blocks/CU; was 512+256 tail at 2/CU).
// Body unchanged -> bit-exact.
// MODE 0: bf16 C; z==0 (Q) scaled by 0.125*log2(e) (exp2 domain).
// MODE 1: fp32 C + residual.
// ---------------------------------------------------------------------------
template <int MODE>
__launch_bounds__(256, 3)
__global__ void gemm_nt(const unsigned short* __restrict__ A,
                        const unsigned short* __restrict__ Bw,
                        void* __restrict__ Cout,
                        const float* __restrict__ resid,
                        int M, int N, int K) {
    __shared__ __align__(16) unsigned short As[128 * 64];
    __shared__ __align__(16) unsigned short Bs[128 * 64];

    const int z  = blockIdx.z;
    const unsigned short* Bp = Bw + (size_t)z * N * K;
    const int m0 = blockIdx.y * 128, n0 = blockIdx.x * 128;
    const int tid  = threadIdx.x;
    const int lane = tid & 63, wv = tid >> 6;
    const int wm = wv >> 1, wn = wv & 1;
    const int quad = lane >> 4, l16 = lane & 15;

    floatx4 acc[4][4] = {};

    const int r0 = lane >> 3;
    const int jc = ((lane & 7) ^ r0) * 8;
    const unsigned short* Ag[4];
    const unsigned short* Bg[4];
    unsigned short* Asd[4];
    unsigned short* Bsd[4];
#pragma unroll
    for (int seg = 0; seg < 4; seg++) {
        const int row = seg * 32 + wv * 8 + r0;        // 0..127
        Ag[seg] = A  + (size_t)(m0 + row) * K + jc;    // + k0 per iter
        Bg[seg] = Bp + (size_t)(n0 + row) * K + jc;
        Asd[seg] = As + (seg * 32 + wv * 8) * 64;      // wave-uniform
        Bsd[seg] = Bs + (seg * 32 + wv * 8) * 64;
    }

    const int pk0 = (quad ^ (l16 & 7)) * 8;
    const int pk1 = ((4 + quad) ^ (l16 & 7)) * 8;

    for (int k0 = 0; k0 < K; k0 += 64) {
        __syncthreads();
#pragma unroll
        for (int seg = 0; seg < 4; seg++) {
            gload16(Ag[seg] + k0, Asd[seg]);
            gload16(Bg[seg] + k0, Bsd[seg]);
        }
        __syncthreads();

#pragma unroll
        for (int h = 0; h < 2; h++) {
            const int pk = h ? pk1 : pk0;
            short8 af[4], bf[4];
#pragma unroll
            for (int i = 0; i < 4; i++)
                af[i] = *(const short8*)(As + (wm * 64 + i * 16 + l16) * 64 + pk);
#pragma unroll
            for (int j = 0; j < 4; j++)
                bf[j] = *(const short8*)(Bs + (wn * 64 + j * 16 + l16) * 64 + pk);
#pragma unroll
            for (int i = 0; i < 4; i++)
#pragma unroll
                for (int j = 0; j < 4; j++)
                    acc[i][j] = mfma16(af[i], bf[j], acc[i][j]);
        }
    }

#pragma unroll
    for (int i = 0; i < 4; i++)
#pragma unroll
        for (int j = 0; j < 4; j++) {
            const int row = m0 + wm * 64 + i * 16 + quad * 4;
            const int col = n0 + wn * 64 + j * 16 + l16;
#pragma unroll
            for (int r = 0; r < 4; r++) {
                float v = acc[i][j][r];
                if (MODE == 0) {
                    if (z == 0) v *= 0.18033688f;   // 0.125 * log2(e)
                    ((unsigned short*)Cout)[(size_t)z * M * N + (size_t)(row + r) * N + col] = f2b(v);
                } else {
                    size_t idx = (size_t)(row + r) * N + col;
                    ((float*)Cout)[idx] = v + resid[idx];
                }
            }
        }
}

// ---------------------------------------------------------------------------
// K2: FUSED column-softmax denominators + scaled V^T — round 10: KEY-SPLIT.
// Keys are independent here (each denominator is its own q-sum; no
// cross-key reduction), so halve keys/block 128 -> 64 (16 per wave, s-loop
// dropped) and double grid 512 -> 1024 = 4 blocks/CU, 16 waves/CU.
// Per-key q-accumulation order is UNCHANGED -> bit-exact vs round 9.
// Phase 1: invl[k] = 1/sum_q exp2(s[q,k]) (K-stationary).
// Phase 2: VT[bh][d][k] = V[b][k][h*64+d] * invl[k], one 64-key group.
// ---------------------------------------------------------------------------
__launch_bounds__(256, 4)
__global__ void stats_vt_kernel(const unsigned short* __restrict__ Qb,
                                const unsigned short* __restrict__ Kb,
                                const unsigned short* __restrict__ Vb,
                                unsigned short* __restrict__ VT) {
    __shared__ __align__(16) unsigned short Qs[64 * 68];  // staging (64) / transpose tile (65)
    __shared__ float s_inv[64];

    const int id = blockIdx.x;                       // 0..1023
    const int bh = (id & 7) + 8 * ((id >> 3) & 3);   // XCD-grouped (same-bh blocks share an XCD)
    const int keyblk = id >> 5;                      // 0..31 (64 keys each)
    const int b = bh >> 4, h = bh & 15;
    const int tid = threadIdx.x, lane = tid & 63, w = tid >> 6;   // w = 0..3
    const int quad = lane >> 4, l16 = lane & 15;
    const int keybase = keyblk * 64 + w * 16;        // 16 keys per wave

    // A-frag: K rows (one 16-key tile x 2 dh-halves), held in regs
    short8 ak0, ak1;
    {
        const unsigned short* Krow = Kb + (size_t)(b * kS + keybase + l16) * kD + h * kDh;
        ak0 = *(const short8*)(Krow + quad * 8);
        ak1 = *(const short8*)(Krow + 32 + quad * 8);
    }

    // staging: wave w covers rows w*16 .. w*16+15 (2 segs of 8 rows);
    // lane covers row seg*8 + (lane>>3), logical 16B chunk (lane&7)^r0
    const int r0 = lane >> 3;
    const int jc = ((lane & 7) ^ r0) * 8;
    const unsigned short* Qg[2];
    unsigned short* Ql[2];
#pragma unroll
    for (int seg = 0; seg < 2; seg++) {
        const int row = w * 16 + seg * 8 + r0;              // 0..63
        Qg[seg] = Qb + (size_t)(b * kS + row) * kD + h * kDh + jc;   // + q0*kD per chunk
        Ql[seg] = Qs + (w * 16 + seg * 8) * 64;             // wave-uniform
    }

    const int pk0 = (quad ^ (l16 & 7)) * 8;
    const int pk1 = ((4 + quad) ^ (l16 & 7)) * 8;

    float lacc[4] = {};

    for (int q0 = 0; q0 < kS; q0 += 64) {
        __syncthreads();
#pragma unroll
        for (int seg = 0; seg < 2; seg++)
            gload16(Qg[seg] + (size_t)q0 * kD, Ql[seg]);
        __syncthreads();

#pragma unroll
        for (int c = 0; c < 4; c++) {
            const unsigned short* row = Qs + (c * 16 + l16) * 64;
            short8 bq0 = *(const short8*)(row + pk0);
            short8 bq1 = *(const short8*)(row + pk1);
            floatx4 t = {0.f, 0.f, 0.f, 0.f};
            t = mfma16(ak0, bq0, t);
            t = mfma16(ak1, bq1, t);
#pragma unroll
            for (int r = 0; r < 4; r++)
                lacc[r] += exp2f(t[r]);
        }
    }

    // reduce across the 16 l16 lanes (q columns) within each quad
#pragma unroll
    for (int off = 1; off <= 8; off <<= 1)
#pragma unroll
        for (int r = 0; r < 4; r++)
            lacc[r] += __shfl_xor(lacc[r], off, 64);

    __syncthreads();   // Qs reads done before tile reuse; also orders s_inv
    if (l16 == 0) {
#pragma unroll
        for (int r = 0; r < 4; r++)
            s_inv[w * 16 + quad * 4 + r] = 1.0f / lacc[r];
    }
    __syncthreads();

    // Phase 2: scaled V^T for this block's 64 keys.
    unsigned short* tile = Qs;   // reuse, stride 65
    {
        const int kr = tid >> 2, dc = (tid & 3) * 16;
        const float iv = s_inv[kr];
        const unsigned short* src =
            Vb + (size_t)(b * kS + keyblk * 64 + kr) * kD + h * kDh + dc;
        unsigned short vs[16];
        *(uint4*)(vs)     = *(const uint4*)(src);
        *(uint4*)(vs + 8) = *(const uint4*)(src + 8);
#pragma unroll
        for (int i = 0; i < 16; i++)
            tile[kr * 65 + dc + i] = f2b(b2f(vs[i]) * iv);
    }
    __syncthreads();
    {
        const int d = tid >> 2, kc = (tid & 3) * 16;
        unsigned short os[16];
#pragma unroll
        for (int j = 0; j < 16; j++) os[j] = tile[(kc + j) * 65 + d];
        unsigned short* dst =
            VT + (size_t)bh * kDh * kS + (size_t)d * kS + keyblk * 64 + kc;
        *(uint4*)(dst)     = *(uint4*)(os);
        *(uint4*)(dst + 8) = *(uint4*)(os + 8);
    }
}

// ---------------------------------------------------------------------------
// K3: ctx = exp2(S) @ VT^T — round 21 (verified r9: 61.6us, absmax 0.03125):
// tile-pair interleave. FROZEN: latency floor at 2 waves/SIMD reached; all
// further levers (key-split, wave repartition) change accumulation order,
// proven fatal to the absmax threshold in round 4.
// ---------------------------------------------------------------------------
__launch_bounds__(256, 2)
__global__ void ctx_kernel(const unsigned short* __restrict__ Qb,
                           const unsigned short* __restrict__ Kb,
                           const unsigned short* __restrict__ VT,
                           unsigned short* __restrict__ Ctx) {
    // [tile][0] = K tile, [tile][1] = VT tile; 32 KB total.
    __shared__ __align__(16) unsigned short Sh[2][2][64 * 64];

    const int id = blockIdx.x;                       // 0..511
    const int bh = (id & 7) + 8 * ((id >> 3) & 3);   // XCD-grouped
    const int qblk = id >> 5;                        // 0..15
    const int b = bh >> 4, h = bh & 15;
    const int tid = threadIdx.x, lane = tid & 63, w = tid >> 6;   // w = 0..3
    const int l32 = lane & 31, hi = lane >> 5;
    const int qbase = qblk * 128 + w * 32;           // 32 q per wave

    // Q-frags (B-operand of QK^T), 4 dh-ksteps: lane: q=l32, dh=kq*16+hi*8
    short8 aq[4];
    {
        const unsigned short* Qrow =
            Qb + (size_t)(b * kS + qbase + l32) * kD + h * kDh + hi * 8;
#pragma unroll
        for (int kq = 0; kq < 4; kq++)
            aq[kq] = *(const short8*)(Qrow + kq * 16);
    }
    floatx16 acc[2] = {};   // PV acc: d-tiles t=0,1 (rows=q via regs, col=lane&31=d)

    const unsigned short* Kbase = Kb + (size_t)(b * kS) * kD + h * kDh;
    const unsigned short* VTb   = VT + (size_t)bh * kDh * kS;

    // staging: 4 waves cover 64 rows, XOR-chunk source (linear LDS dest)
    const int r0 = lane >> 3;
    const int jc = ((lane & 7) ^ r0) * 8;
    const unsigned short* Kg[2];
    const unsigned short* Vg[2];
    int loff[2];
#pragma unroll
    for (int seg = 0; seg < 2; seg++) {
        const int row = w * 16 + seg * 8 + r0;         // 0..63
        Kg[seg] = Kbase + (size_t)row * kD + jc;       // + k0*kD per chunk
        Vg[seg] = VTb + (size_t)row * kS + jc;         // + k0 per chunk
        loff[seg] = (w * 16 + seg * 8) * 64;           // wave-uniform
    }

    const int x7 = l32 & 7;    // row&7 for the chunk swizzle

    for (int k0 = 0; k0 < kS; k0 += 128) {
        // stage tile k0 into Sh[0], tile k0+64 into Sh[1]
#pragma unroll
        for (int seg = 0; seg < 2; seg++) {
            gload16(Kg[seg] + (size_t)k0 * kD,        &Sh[0][0][loff[seg]]);
            gload16(Vg[seg] + k0,                     &Sh[0][1][loff[seg]]);
            gload16(Kg[seg] + (size_t)(k0 + 64) * kD, &Sh[1][0][loff[seg]]);
            gload16(Vg[seg] + (k0 + 64),              &Sh[1][1][loff[seg]]);
        }
        __syncthreads();   // implicit vmcnt(0): both tiles landed

        // two round-3-verbatim compute bodies, no barrier between ->
        // compiler can interleave tile1's ds_read/QK^T with tile0's
        // exp2/pack/PV. Accumulation order preserved (tb=0 then tb=1).
#pragma unroll
        for (int tb = 0; tb < 2; tb++) {
            const unsigned short* Ks  = Sh[tb][0];
            const unsigned short* VTs = Sh[tb][1];

            // QK^T: sc[s] = K-tile(s) x Q -> D[key][q], col=lane&31=q,
            // key = (r&3) + 8*(r>>2) + 4*hi (+32s)
            floatx16 sc[2];
#pragma unroll
            for (int s = 0; s < 2; s++) {
                const unsigned short* arow = Ks + (s * 32 + l32) * 64;
                floatx16 t = {0.f,0.f,0.f,0.f,0.f,0.f,0.f,0.f,
                              0.f,0.f,0.f,0.f,0.f,0.f,0.f,0.f};
#pragma unroll
                for (int kq = 0; kq < 4; kq++) {
                    short8 af = *(const short8*)(arow + ((2 * kq + hi) ^ x7) * 8);
                    t = mfma32(af, aq[kq], t);
                }
                sc[s] = t;
            }

            // P build fully in-register: exp2 -> truncating bf16 pack ->
            // permlane32_swap. pa[kk] = A-frag (q=l32, keys kk*16+hi*8..+8).
            short8 pa[4];
#pragma unroll
            for (int s = 0; s < 2; s++) {
                float e[16];
#pragma unroll
                for (int r = 0; r < 16; r++) e[r] = exp2f(sc[s][r]);
                unsigned p0 = packbf(e[0],  e[1]),  p1 = packbf(e[2],  e[3]);
                unsigned p2 = packbf(e[4],  e[5]),  p3 = packbf(e[6],  e[7]);
                unsigned p4 = packbf(e[8],  e[9]),  p5 = packbf(e[10], e[11]);
                unsigned p6 = packbf(e[12], e[13]), p7 = packbf(e[14], e[15]);
                asm volatile("v_permlane32_swap_b32 %0, %1" : "+v"(p0), "+v"(p2));
                asm volatile("v_permlane32_swap_b32 %0, %1" : "+v"(p1), "+v"(p3));
                asm volatile("v_permlane32_swap_b32 %0, %1" : "+v"(p4), "+v"(p6));
                asm volatile("v_permlane32_swap_b32 %0, %1" : "+v"(p5), "+v"(p7));
                union { unsigned u[4]; short8 v; } f0, f1;
                f0.u[0] = p0; f0.u[1] = p1; f0.u[2] = p2; f0.u[3] = p3;
                f1.u[0] = p4; f1.u[1] = p5; f1.u[2] = p6; f1.u[3] = p7;
                pa[2 * s]     = f0.v;
                pa[2 * s + 1] = f1.v;
            }

            // PV: acc[t] += P x VT-tile(t) -> D[q][d]
#pragma unroll
            for (int t = 0; t < 2; t++) {
                const unsigned short* brow = VTs + (t * 32 + l32) * 64;
#pragma unroll
                for (int kk = 0; kk < 4; kk++) {
                    short8 bv = *(const short8*)(brow + ((2 * kk + hi) ^ x7) * 8);
                    acc[t] = mfma32(pa[kk], bv, acc[t]);
                }
            }
        }

        __syncthreads();   // all reads done before next stage overwrites
    }

    // D layout: col=lane&31 = d_local (within tile t), row q = (r&3)+8*(r>>2)+4*hi
#pragma unroll
    for (int t = 0; t < 2; t++)
#pragma unroll
        for (int rg = 0; rg < 4; rg++)
#pragma unroll
            for (int j = 0; j < 4; j++) {
                const int q = qbase + rg * 8 + hi * 4 + j;
                const int d = h * kDh + t * 32 + l32;
                Ctx[(size_t)(b * kS + q) * kD + d] = f2b(acc[t][rg * 4 + j]);
            }
}

// ---------------------------------------------------------------------------
// K4: row LayerNorm
// ---------------------------------------------------------------------------
__global__ void ln_kernel(const float* __restrict__ R, const float* __restrict__ gamma,
                          const float* __restrict__ beta, float* __restrict__ out) {
    const int row = blockIdx.x;
    const int tid = threadIdx.x;
    const float4 v = ((const float4*)(R + (size_t)row * kD))[tid];
    float s  = v.x + v.y + v.z + v.w;
    float ss = v.x * v.x + v.y * v.y + v.z * v.z + v.w * v.w;
#pragma unroll
    for (int off = 32; off > 0; off >>= 1) {
        s  += __shfl_down(s, off, 64);
        ss += __shfl_down(ss, off, 64);
    }
    __shared__ float ws_s[4], ws_ss[4];
    __shared__ float mu_sh, inv_sh;
    const int lane = tid & 63, w = tid >> 6;
    if (lane == 0) { ws_s[w] = s; ws_ss[w] = ss; }
    __syncthreads();
    if (tid == 0) {
        float S1 = ws_s[0] + ws_s[1] + ws_s[2] + ws_s[3];
        float S2 = ws_ss[0] + ws_ss[1] + ws_ss[2] + ws_ss[3];
        float mu = S1 * (1.0f / kD);
        float var = S2 * (1.0f / kD) - mu * mu;
        mu_sh = mu;
        inv_sh = rsqrtf(var + 1e-5f);
    }
    __syncthreads();
    const float mu = mu_sh, inv = inv_sh;
    const float4 g  = ((const float4*)gamma)[tid];
    const float4 bb = ((const float4*)beta)[tid];
    float4 o;
    o.x = (v.x - mu) * inv * g.x + bb.x;
    o.y = (v.y - mu) * inv * g.y + bb.y;
    o.z = (v.z - mu) * inv * g.z + bb.z;
    o.w = (v.w - mu) * inv * g.w + bb.w;
    ((float4*)(out + (size_t)row * kD))[tid] = o;
}

// ---------------------------------------------------------------------------
// Workspace layout (64 MB peak, aliasing is stream-ordered-safe):
//   [0,   8MB)  Xb bf16
//   [8,  16MB)  Wb bf16 wq|wk|wv|wo
//   [16, 40MB)  QKV bf16 Q|K|V  (Q pre-scaled by 0.125*log2e)
//   [40, 48MB)  Ctx bf16
//   [48, 64MB)  VT bf16 [32][64][2048]; ALIASES R (written strictly later)
// ---------------------------------------------------------------------------
extern "C" void kernel_launch(void* const* d_in, const int* in_sizes, int n_in,
                              void* d_out, int out_size, void* d_ws, size_t ws_size,
                              hipStream_t stream) {
    const float* x     = (const float*)d_in[0];
    const float* wq    = (const float*)d_in[1];
    const float* wk    = (const float*)d_in[2];
    const float* wv    = (const float*)d_in[3];
    const float* wo    = (const float*)d_in[4];
    const float* gamma = (const float*)d_in[5];
    const float* beta  = (const float*)d_in[6];
    float* out = (float*)d_out;

    char* ws = (char*)d_ws;
    unsigned short* Xb  = (unsigned short*)(ws);
    unsigned short* Wb  = (unsigned short*)(ws + (8u  << 20));
    unsigned short* QKV = (unsigned short*)(ws + (16u << 20));
    unsigned short* Qb  = QKV;
    unsigned short* Kb  = QKV + (size_t)kBS * kD;
    unsigned short* Vb  = QKV + (size_t)2 * kBS * kD;
    unsigned short* Ctx = (unsigned short*)(ws + (40u << 20));
    unsigned short* VT  = (unsigned short*)(ws + (48u << 20));
    float* R            = (float*)(ws + (48u << 20));  // aliases VT

    convert_kernel<<<8192, 256, 0, stream>>>(x, wq, wk, wv, wo, Xb, Wb);

    gemm_nt<0><<<dim3(kD / 128, kBS / 128, 3), 256, 0, stream>>>(
        Xb, Wb, QKV, nullptr, kBS, kD, kD);

    stats_vt_kernel<<<1024, 256, 0, stream>>>(Qb, Kb, Vb, VT);

    ctx_kernel<<<512, 256, 0, stream>>>(Qb, Kb, VT, Ctx);

    gemm_nt<1><<<dim3(kD / 128, kBS / 128, 1), 256, 0, stream>>>(
        Ctx, Wb + (size_t)3 * kD * kD, R, x, kBS, kD, kD);

    ln_kernel<<<kBS, 256, 0, stream>>>(R, gamma, beta, out);
}

// Round 11
// 237.949 us; speedup vs baseline: 1.0304x; 1.0050x over previous
//
#include <hip/hip_runtime.h>
#include <hip/hip_bf16.h>

// Problem constants
constexpr int kB   = 2;
constexpr int kS   = 2048;
constexpr int kD   = 1024;
constexpr int kH   = 16;
constexpr int kDh  = 64;
constexpr int kBS  = kB * kS;          // 4096 rows

typedef __attribute__((ext_vector_type(8))) short short8;   // 8 bf16 = 4 VGPRs
typedef __attribute__((ext_vector_type(4))) float floatx4;  // MFMA acc 16x16
typedef __attribute__((ext_vector_type(16))) float floatx16; // MFMA acc 32x32

__device__ inline unsigned short f2b(float f) {
    __hip_bfloat16 h = __float2bfloat16(f);
    return *reinterpret_cast<unsigned short*>(&h);
}

__device__ inline float b2f(unsigned short u) {
    union { unsigned u; float f; } cv;
    cv.u = (unsigned)u << 16;
    return cv.f;
}

__device__ inline floatx4 mfma16(short8 a, short8 b, floatx4 c) {
    return __builtin_amdgcn_mfma_f32_16x16x32_bf16(a, b, c, 0, 0, 0);
}

__device__ inline floatx16 mfma32(short8 a, short8 b, floatx16 c) {
    return __builtin_amdgcn_mfma_f32_32x32x16_bf16(a, b, c, 0, 0, 0);
}

// truncating pack of two f32 -> one u32 of 2 bf16 (lo = a, hi = b).
// Truncating is part of the round-3 verified arithmetic — do not change
// (absmax 0.03125 depends on reproducing it bit-exactly).
__device__ inline unsigned packbf(float a, float b) {
    union { float f; unsigned u; } x, y;
    x.f = a; y.f = b;
    return (x.u >> 16) | (y.u & 0xffff0000u);
}

// async global->LDS, 16B per lane; LDS dest = wave-uniform base + lane*16
__device__ inline void gload16(const unsigned short* g, unsigned short* l) {
    __builtin_amdgcn_global_load_lds(
        (const __attribute__((address_space(1))) void*)g,
        (__attribute__((address_space(3))) void*)l, 16, 0, 0);
}

// ---------------------------------------------------------------------------
// K0: fp32 -> bf16 conversion of x (4M elems) and the 4 weights (4 x 1M elems)
// Round 11: 2048 blocks + 4-step grid-stride (guideline 11); body unchanged.
// ---------------------------------------------------------------------------
__global__ void convert_kernel(const float* __restrict__ x,
                               const float* __restrict__ wq, const float* __restrict__ wk,
                               const float* __restrict__ wv, const float* __restrict__ wo,
                               unsigned short* __restrict__ xb, unsigned short* __restrict__ wb) {
#pragma unroll
    for (int it = 0; it < 4; it++) {
        int gid = blockIdx.x * blockDim.x + threadIdx.x + it * (2048 * 256);
        long i4 = (long)gid * 4;
        const float* src;
        unsigned short* dst;
        long off;
        if (i4 < (long)kBS * kD) {
            src = x; dst = xb; off = i4;
        } else {
            long w = i4 - (long)kBS * kD;
            int sel = (int)(w >> 20);
            off = w & 1048575;
            src = (sel == 0) ? wq : (sel == 1) ? wk : (sel == 2) ? wv : wo;
            dst = wb + (long)sel * 1048576;
        }
        float4 v = *(const float4*)(src + off);
        ushort4 o;
        o.x = f2b(v.x); o.y = f2b(v.y); o.z = f2b(v.z); o.w = f2b(v.w);
        *(ushort4*)(dst + off) = o;
    }
}

// ---------------------------------------------------------------------------
// K1: NT GEMM  C[M,N] = A[M,K] @ B[N,K]^T   (bf16 in, fp32 accum)
// BK=64: 32 MFMAs per barrier-pair. Staging via global_load_lds w=16 with
// 8-chunk XOR swizzle; 32 KB LDS. __launch_bounds__(256,3): MODE-0's 768
// blocks fit one resident generation (3 blocks/CU). Body bit-exact since r0.
// MODE 0: bf16 C; z==0 (Q) scaled by 0.125*log2(e) (exp2 domain).
// MODE 1: fp32 C + residual.
// ---------------------------------------------------------------------------
template <int MODE>
__launch_bounds__(256, 3)
__global__ void gemm_nt(const unsigned short* __restrict__ A,
                        const unsigned short* __restrict__ Bw,
                        void* __restrict__ Cout,
                        const float* __restrict__ resid,
                        int M, int N, int K) {
    __shared__ __align__(16) unsigned short As[128 * 64];
    __shared__ __align__(16) unsigned short Bs[128 * 64];

    const int z  = blockIdx.z;
    const unsigned short* Bp = Bw + (size_t)z * N * K;
    const int m0 = blockIdx.y * 128, n0 = blockIdx.x * 128;
    const int tid  = threadIdx.x;
    const int lane = tid & 63, wv = tid >> 6;
    const int wm = wv >> 1, wn = wv & 1;
    const int quad = lane >> 4, l16 = lane & 15;

    floatx4 acc[4][4] = {};

    const int r0 = lane >> 3;
    const int jc = ((lane & 7) ^ r0) * 8;
    const unsigned short* Ag[4];
    const unsigned short* Bg[4];
    unsigned short* Asd[4];
    unsigned short* Bsd[4];
#pragma unroll
    for (int seg = 0; seg < 4; seg++) {
        const int row = seg * 32 + wv * 8 + r0;        // 0..127
        Ag[seg] = A  + (size_t)(m0 + row) * K + jc;    // + k0 per iter
        Bg[seg] = Bp + (size_t)(n0 + row) * K + jc;
        Asd[seg] = As + (seg * 32 + wv * 8) * 64;      // wave-uniform
        Bsd[seg] = Bs + (seg * 32 + wv * 8) * 64;
    }

    const int pk0 = (quad ^ (l16 & 7)) * 8;
    const int pk1 = ((4 + quad) ^ (l16 & 7)) * 8;

    for (int k0 = 0; k0 < K; k0 += 64) {
        __syncthreads();
#pragma unroll
        for (int seg = 0; seg < 4; seg++) {
            gload16(Ag[seg] + k0, Asd[seg]);
            gload16(Bg[seg] + k0, Bsd[seg]);
        }
        __syncthreads();

#pragma unroll
        for (int h = 0; h < 2; h++) {
            const int pk = h ? pk1 : pk0;
            short8 af[4], bf[4];
#pragma unroll
            for (int i = 0; i < 4; i++)
                af[i] = *(const short8*)(As + (wm * 64 + i * 16 + l16) * 64 + pk);
#pragma unroll
            for (int j = 0; j < 4; j++)
                bf[j] = *(const short8*)(Bs + (wn * 64 + j * 16 + l16) * 64 + pk);
#pragma unroll
            for (int i = 0; i < 4; i++)
#pragma unroll
                for (int j = 0; j < 4; j++)
                    acc[i][j] = mfma16(af[i], bf[j], acc[i][j]);
        }
    }

#pragma unroll
    for (int i = 0; i < 4; i++)
#pragma unroll
        for (int j = 0; j < 4; j++) {
            const int row = m0 + wm * 64 + i * 16 + quad * 4;
            const int col = n0 + wn * 64 + j * 16 + l16;
#pragma unroll
            for (int r = 0; r < 4; r++) {
                float v = acc[i][j][r];
                if (MODE == 0) {
                    if (z == 0) v *= 0.18033688f;   // 0.125 * log2(e)
                    ((unsigned short*)Cout)[(size_t)z * M * N + (size_t)(row + r) * N + col] = f2b(v);
                } else {
                    size_t idx = (size_t)(row + r) * N + col;
                    ((float*)Cout)[idx] = v + resid[idx];
                }
            }
        }
}

// ---------------------------------------------------------------------------
// K2: FUSED column-softmax denominators + scaled V^T — round 11: key-split
// (r10, 64 keys/block, grid 1024, 4 blocks/CU) + TILE-PAIR INTERLEAVE
// (r9-verified ctx pattern): stage two 64-q tiles per barrier-pair, run the
// two compute bodies back-to-back with no barrier between -> tile1's
// ds_read/MFMA overlap tile0's exp2 chain. Barriers per 2048-q sweep
// halve (64 -> 32). Per-key q-accumulation order UNCHANGED (q ascending,
// tile q0 then q0+64 = same sequence as r10) -> bit-exact.
// Phase 1: invl[k] = 1/sum_q exp2(s[q,k]) (K-stationary).
// Phase 2: VT[bh][d][k] = V[b][k][h*64+d] * invl[k].
// ---------------------------------------------------------------------------
__launch_bounds__(256, 4)
__global__ void stats_vt_kernel(const unsigned short* __restrict__ Qb,
                                const unsigned short* __restrict__ Kb,
                                const unsigned short* __restrict__ Vb,
                                unsigned short* __restrict__ VT) {
    // two staging tiles; Qs[0] reused as the 64x65 transpose tile in phase 2
    __shared__ __align__(16) unsigned short Qs[2][64 * 66];
    __shared__ float s_inv[64];

    const int id = blockIdx.x;                       // 0..1023
    const int bh = (id & 7) + 8 * ((id >> 3) & 3);   // XCD-grouped
    const int keyblk = id >> 5;                      // 0..31 (64 keys each)
    const int b = bh >> 4, h = bh & 15;
    const int tid = threadIdx.x, lane = tid & 63, w = tid >> 6;   // w = 0..3
    const int quad = lane >> 4, l16 = lane & 15;
    const int keybase = keyblk * 64 + w * 16;        // 16 keys per wave

    // A-frag: K rows (one 16-key tile x 2 dh-halves), held in regs
    short8 ak0, ak1;
    {
        const unsigned short* Krow = Kb + (size_t)(b * kS + keybase + l16) * kD + h * kDh;
        ak0 = *(const short8*)(Krow + quad * 8);
        ak1 = *(const short8*)(Krow + 32 + quad * 8);
    }

    // staging: wave w covers rows w*16 .. w*16+15 (2 segs of 8 rows);
    // lane covers row seg*8 + (lane>>3), logical 16B chunk (lane&7)^r0
    const int r0 = lane >> 3;
    const int jc = ((lane & 7) ^ r0) * 8;
    const unsigned short* Qg[2];
    int loff[2];
#pragma unroll
    for (int seg = 0; seg < 2; seg++) {
        const int row = w * 16 + seg * 8 + r0;              // 0..63
        Qg[seg] = Qb + (size_t)(b * kS + row) * kD + h * kDh + jc;   // + q0*kD per chunk
        loff[seg] = (w * 16 + seg * 8) * 64;                // wave-uniform
    }

    const int pk0 = (quad ^ (l16 & 7)) * 8;
    const int pk1 = ((4 + quad) ^ (l16 & 7)) * 8;

    float lacc[4] = {};

    for (int q0 = 0; q0 < kS; q0 += 128) {
        __syncthreads();   // previous tiles' reads complete before overwrite
#pragma unroll
        for (int seg = 0; seg < 2; seg++) {
            gload16(Qg[seg] + (size_t)q0 * kD,        &Qs[0][loff[seg]]);
            gload16(Qg[seg] + (size_t)(q0 + 64) * kD, &Qs[1][loff[seg]]);
        }
        __syncthreads();   // implicit vmcnt(0): both tiles landed

#pragma unroll
        for (int tb = 0; tb < 2; tb++) {
#pragma unroll
            for (int c = 0; c < 4; c++) {
                const unsigned short* row = &Qs[tb][(c * 16 + l16) * 64];
                short8 bq0 = *(const short8*)(row + pk0);
                short8 bq1 = *(const short8*)(row + pk1);
                floatx4 t = {0.f, 0.f, 0.f, 0.f};
                t = mfma16(ak0, bq0, t);
                t = mfma16(ak1, bq1, t);
#pragma unroll
                for (int r = 0; r < 4; r++)
                    lacc[r] += exp2f(t[r]);
            }
        }
    }

    // reduce across the 16 l16 lanes (q columns) within each quad
#pragma unroll
    for (int off = 1; off <= 8; off <<= 1)
#pragma unroll
        for (int r = 0; r < 4; r++)
            lacc[r] += __shfl_xor(lacc[r], off, 64);

    __syncthreads();   // Qs reads done before tile reuse; also orders s_inv
    if (l16 == 0) {
#pragma unroll
        for (int r = 0; r < 4; r++)
            s_inv[w * 16 + quad * 4 + r] = 1.0f / lacc[r];
    }
    __syncthreads();

    // Phase 2: scaled V^T for this block's 64 keys.
    unsigned short* tile = &Qs[0][0];   // reuse, stride 65 (4160 <= 4224 OK)
    {
        const int kr = tid >> 2, dc = (tid & 3) * 16;
        const float iv = s_inv[kr];
        const unsigned short* src =
            Vb + (size_t)(b * kS + keyblk * 64 + kr) * kD + h * kDh + dc;
        unsigned short vs[16];
        *(uint4*)(vs)     = *(const uint4*)(src);
        *(uint4*)(vs + 8) = *(const uint4*)(src + 8);
#pragma unroll
        for (int i = 0; i < 16; i++)
            tile[kr * 65 + dc + i] = f2b(b2f(vs[i]) * iv);
    }
    __syncthreads();
    {
        const int d = tid >> 2, kc = (tid & 3) * 16;
        unsigned short os[16];
#pragma unroll
        for (int j = 0; j < 16; j++) os[j] = tile[(kc + j) * 65 + d];
        unsigned short* dst =
            VT + (size_t)bh * kDh * kS + (size_t)d * kS + keyblk * 64 + kc;
        *(uint4*)(dst)     = *(uint4*)(os);
        *(uint4*)(dst + 8) = *(uint4*)(os + 8);
    }
}

// ---------------------------------------------------------------------------
// K3: ctx = exp2(S) @ VT^T — round 21 (verified r9: 61.6us, absmax 0.03125):
// tile-pair interleave. FROZEN: latency floor at 2 waves/SIMD reached; all
// further levers (key-split, wave repartition) change accumulation order,
// proven fatal to the absmax threshold in round 4. r9/r10 same-source swing
// 61.6<->68.3us = codegen/noise band; do not chase.
// ---------------------------------------------------------------------------
__launch_bounds__(256, 2)
__global__ void ctx_kernel(const unsigned short* __restrict__ Qb,
                           const unsigned short* __restrict__ Kb,
                           const unsigned short* __restrict__ VT,
                           unsigned short* __restrict__ Ctx) {
    // [tile][0] = K tile, [tile][1] = VT tile; 32 KB total.
    __shared__ __align__(16) unsigned short Sh[2][2][64 * 64];

    const int id = blockIdx.x;                       // 0..511
    const int bh = (id & 7) + 8 * ((id >> 3) & 3);   // XCD-grouped
    const int qblk = id >> 5;                        // 0..15
    const int b = bh >> 4, h = bh & 15;
    const int tid = threadIdx.x, lane = tid & 63, w = tid >> 6;   // w = 0..3
    const int l32 = lane & 31, hi = lane >> 5;
    const int qbase = qblk * 128 + w * 32;           // 32 q per wave

    // Q-frags (B-operand of QK^T), 4 dh-ksteps: lane: q=l32, dh=kq*16+hi*8
    short8 aq[4];
    {
        const unsigned short* Qrow =
            Qb + (size_t)(b * kS + qbase + l32) * kD + h * kDh + hi * 8;
#pragma unroll
        for (int kq = 0; kq < 4; kq++)
            aq[kq] = *(const short8*)(Qrow + kq * 16);
    }
    floatx16 acc[2] = {};   // PV acc: d-tiles t=0,1 (rows=q via regs, col=lane&31=d)

    const unsigned short* Kbase = Kb + (size_t)(b * kS) * kD + h * kDh;
    const unsigned short* VTb   = VT + (size_t)bh * kDh * kS;

    // staging: 4 waves cover 64 rows, XOR-chunk source (linear LDS dest)
    const int r0 = lane >> 3;
    const int jc = ((lane & 7) ^ r0) * 8;
    const unsigned short* Kg[2];
    const unsigned short* Vg[2];
    int loff[2];
#pragma unroll
    for (int seg = 0; seg < 2; seg++) {
        const int row = w * 16 + seg * 8 + r0;         // 0..63
        Kg[seg] = Kbase + (size_t)row * kD + jc;       // + k0*kD per chunk
        Vg[seg] = VTb + (size_t)row * kS + jc;         // + k0 per chunk
        loff[seg] = (w * 16 + seg * 8) * 64;           // wave-uniform
    }

    const int x7 = l32 & 7;    // row&7 for the chunk swizzle

    for (int k0 = 0; k0 < kS; k0 += 128) {
        // stage tile k0 into Sh[0], tile k0+64 into Sh[1]
#pragma unroll
        for (int seg = 0; seg < 2; seg++) {
            gload16(Kg[seg] + (size_t)k0 * kD,        &Sh[0][0][loff[seg]]);
            gload16(Vg[seg] + k0,                     &Sh[0][1][loff[seg]]);
            gload16(Kg[seg] + (size_t)(k0 + 64) * kD, &Sh[1][0][loff[seg]]);
            gload16(Vg[seg] + (k0 + 64),              &Sh[1][1][loff[seg]]);
        }
        __syncthreads();   // implicit vmcnt(0): both tiles landed

        // two round-3-verbatim compute bodies, no barrier between ->
        // compiler can interleave tile1's ds_read/QK^T with tile0's
        // exp2/pack/PV. Accumulation order preserved (tb=0 then tb=1).
#pragma unroll
        for (int tb = 0; tb < 2; tb++) {
            const unsigned short* Ks  = Sh[tb][0];
            const unsigned short* VTs = Sh[tb][1];

            // QK^T: sc[s] = K-tile(s) x Q -> D[key][q], col=lane&31=q,
            // key = (r&3) + 8*(r>>2) + 4*hi (+32s)
            floatx16 sc[2];
#pragma unroll
            for (int s = 0; s < 2; s++) {
                const unsigned short* arow = Ks + (s * 32 + l32) * 64;
                floatx16 t = {0.f,0.f,0.f,0.f,0.f,0.f,0.f,0.f,
                              0.f,0.f,0.f,0.f,0.f,0.f,0.f,0.f};
#pragma unroll
                for (int kq = 0; kq < 4; kq++) {
                    short8 af = *(const short8*)(arow + ((2 * kq + hi) ^ x7) * 8);
                    t = mfma32(af, aq[kq], t);
                }
                sc[s] = t;
            }

            // P build fully in-register: exp2 -> truncating bf16 pack ->
            // permlane32_swap. pa[kk] = A-frag (q=l32, keys kk*16+hi*8..+8).
            short8 pa[4];
#pragma unroll
            for (int s = 0; s < 2; s++) {
                float e[16];
#pragma unroll
                for (int r = 0; r < 16; r++) e[r] = exp2f(sc[s][r]);
                unsigned p0 = packbf(e[0],  e[1]),  p1 = packbf(e[2],  e[3]);
                unsigned p2 = packbf(e[4],  e[5]),  p3 = packbf(e[6],  e[7]);
                unsigned p4 = packbf(e[8],  e[9]),  p5 = packbf(e[10], e[11]);
                unsigned p6 = packbf(e[12], e[13]), p7 = packbf(e[14], e[15]);
                asm volatile("v_permlane32_swap_b32 %0, %1" : "+v"(p0), "+v"(p2));
                asm volatile("v_permlane32_swap_b32 %0, %1" : "+v"(p1), "+v"(p3));
                asm volatile("v_permlane32_swap_b32 %0, %1" : "+v"(p4), "+v"(p6));
                asm volatile("v_permlane32_swap_b32 %0, %1" : "+v"(p5), "+v"(p7));
                union { unsigned u[4]; short8 v; } f0, f1;
                f0.u[0] = p0; f0.u[1] = p1; f0.u[2] = p2; f0.u[3] = p3;
                f1.u[0] = p4; f1.u[1] = p5; f1.u[2] = p6; f1.u[3] = p7;
                pa[2 * s]     = f0.v;
                pa[2 * s + 1] = f1.v;
            }

            // PV: acc[t] += P x VT-tile(t) -> D[q][d]
#pragma unroll
            for (int t = 0; t < 2; t++) {
                const unsigned short* brow = VTs + (t * 32 + l32) * 64;
#pragma unroll
                for (int kk = 0; kk < 4; kk++) {
                    short8 bv = *(const short8*)(brow + ((2 * kk + hi) ^ x7) * 8);
                    acc[t] = mfma32(pa[kk], bv, acc[t]);
                }
            }
        }

        __syncthreads();   // all reads done before next stage overwrites
    }

    // D layout: col=lane&31 = d_local (within tile t), row q = (r&3)+8*(r>>2)+4*hi
#pragma unroll
    for (int t = 0; t < 2; t++)
#pragma unroll
        for (int rg = 0; rg < 4; rg++)
#pragma unroll
            for (int j = 0; j < 4; j++) {
                const int q = qbase + rg * 8 + hi * 4 + j;
                const int d = h * kDh + t * 32 + l32;
                Ctx[(size_t)(b * kS + q) * kD + d] = f2b(acc[t][rg * 4 + j]);
            }
}

// ---------------------------------------------------------------------------
// K4: row LayerNorm
// ---------------------------------------------------------------------------
__global__ void ln_kernel(const float* __restrict__ R, const float* __restrict__ gamma,
                          const float* __restrict__ beta, float* __restrict__ out) {
    const int row = blockIdx.x;
    const int tid = threadIdx.x;
    const float4 v = ((const float4*)(R + (size_t)row * kD))[tid];
    float s  = v.x + v.y + v.z + v.w;
    float ss = v.x * v.x + v.y * v.y + v.z * v.z + v.w * v.w;
#pragma unroll
    for (int off = 32; off > 0; off >>= 1) {
        s  += __shfl_down(s, off, 64);
        ss += __shfl_down(ss, off, 64);
    }
    __shared__ float ws_s[4], ws_ss[4];
    __shared__ float mu_sh, inv_sh;
    const int lane = tid & 63, w = tid >> 6;
    if (lane == 0) { ws_s[w] = s; ws_ss[w] = ss; }
    __syncthreads();
    if (tid == 0) {
        float S1 = ws_s[0] + ws_s[1] + ws_s[2] + ws_s[3];
        float S2 = ws_ss[0] + ws_ss[1] + ws_ss[2] + ws_ss[3];
        float mu = S1 * (1.0f / kD);
        float var = S2 * (1.0f / kD) - mu * mu;
        mu_sh = mu;
        inv_sh = rsqrtf(var + 1e-5f);
    }
    __syncthreads();
    const float mu = mu_sh, inv = inv_sh;
    const float4 g  = ((const float4*)gamma)[tid];
    const float4 bb = ((const float4*)beta)[tid];
    float4 o;
    o.x = (v.x - mu) * inv * g.x + bb.x;
    o.y = (v.y - mu) * inv * g.y + bb.y;
    o.z = (v.z - mu) * inv * g.z + bb.z;
    o.w = (v.w - mu) * inv * g.w + bb.w;
    ((float4*)(out + (size_t)row * kD))[tid] = o;
}

// ---------------------------------------------------------------------------
// Workspace layout (64 MB peak, aliasing is stream-ordered-safe):
//   [0,   8MB)  Xb bf16
//   [8,  16MB)  Wb bf16 wq|wk|wv|wo
//   [16, 40MB)  QKV bf16 Q|K|V  (Q pre-scaled by 0.125*log2e)
//   [40, 48MB)  Ctx bf16
//   [48, 64MB)  VT bf16 [32][64][2048]; ALIASES R (written strictly later)
// ---------------------------------------------------------------------------
extern "C" void kernel_launch(void* const* d_in, const int* in_sizes, int n_in,
                              void* d_out, int out_size, void* d_ws, size_t ws_size,
                              hipStream_t stream) {
    const float* x     = (const float*)d_in[0];
    const float* wq    = (const float*)d_in[1];
    const float* wk    = (const float*)d_in[2];
    const float* wv    = (const float*)d_in[3];
    const float* wo    = (const float*)d_in[4];
    const float* gamma = (const float*)d_in[5];
    const float* beta  = (const float*)d_in[6];
    float* out = (float*)d_out;

    char* ws = (char*)d_ws;
    unsigned short* Xb  = (unsigned short*)(ws);
    unsigned short* Wb  = (unsigned short*)(ws + (8u  << 20));
    unsigned short* QKV = (unsigned short*)(ws + (16u << 20));
    unsigned short* Qb  = QKV;
    unsigned short* Kb  = QKV + (size_t)kBS * kD;
    unsigned short* Vb  = QKV + (size_t)2 * kBS * kD;
    unsigned short* Ctx = (unsigned short*)(ws + (40u << 20));
    unsigned short* VT  = (unsigned short*)(ws + (48u << 20));
    float* R            = (float*)(ws + (48u << 20));  // aliases VT

    convert_kernel<<<2048, 256, 0, stream>>>(x, wq, wk, wv, wo, Xb, Wb);

    gemm_nt<0><<<dim3(kD / 128, kBS / 128, 3), 256, 0, stream>>>(
        Xb, Wb, QKV, nullptr, kBS, kD, kD);

    stats_vt_kernel<<<1024, 256, 0, stream>>>(Qb, Kb, Vb, VT);

    ctx_kernel<<<512, 256, 0, stream>>>(Qb, Kb, VT, Ctx);

    gemm_nt<1><<<dim3(kD / 128, kBS / 128, 1), 256, 0, stream>>>(
        Ctx, Wb + (size_t)3 * kD * kD, R, x, kBS, kD, kD);

    ln_kernel<<<kBS, 256, 0, stream>>>(R, gamma, beta, out);
}

// Round 13
// 235.547 us; speedup vs baseline: 1.0409x; 1.0102x over previous
//
#include <hip/hip_runtime.h>
#include <hip/hip_bf16.h>

// Problem constants
constexpr int kB   = 2;
constexpr int kS   = 2048;
constexpr int kD   = 1024;
constexpr int kH   = 16;
constexpr int kDh  = 64;
constexpr int kBS  = kB * kS;          // 4096 rows

typedef __attribute__((ext_vector_type(8))) short short8;   // 8 bf16 = 4 VGPRs
typedef __attribute__((ext_vector_type(4))) float floatx4;  // MFMA acc 16x16
typedef __attribute__((ext_vector_type(16))) float floatx16; // MFMA acc 32x32

__device__ inline unsigned short f2b(float f) {
    __hip_bfloat16 h = __float2bfloat16(f);
    return *reinterpret_cast<unsigned short*>(&h);
}

__device__ inline float b2f(unsigned short u) {
    union { unsigned u; float f; } cv;
    cv.u = (unsigned)u << 16;
    return cv.f;
}

__device__ inline floatx4 mfma16(short8 a, short8 b, floatx4 c) {
    return __builtin_amdgcn_mfma_f32_16x16x32_bf16(a, b, c, 0, 0, 0);
}

__device__ inline floatx16 mfma32(short8 a, short8 b, floatx16 c) {
    return __builtin_amdgcn_mfma_f32_32x32x16_bf16(a, b, c, 0, 0, 0);
}

// truncating pack of two f32 -> one u32 of 2 bf16 (lo = a, hi = b).
// Truncating is part of the round-3 verified arithmetic — do not change
// (absmax 0.03125 depends on reproducing it bit-exactly).
__device__ inline unsigned packbf(float a, float b) {
    union { float f; unsigned u; } x, y;
    x.f = a; y.f = b;
    return (x.u >> 16) | (y.u & 0xffff0000u);
}

// async global->LDS, 16B per lane; LDS dest = wave-uniform base + lane*16
__device__ inline void gload16(const unsigned short* g, unsigned short* l) {
    __builtin_amdgcn_global_load_lds(
        (const __attribute__((address_space(1))) void*)g,
        (__attribute__((address_space(3))) void*)l, 16, 0, 0);
}

// ---------------------------------------------------------------------------
// K0: fp32 -> bf16 conversion of x (4M elems) and the 4 weights (4 x 1M elems)
// 2048 blocks + 4-step grid-stride (guideline 11).
// ---------------------------------------------------------------------------
__global__ void convert_kernel(const float* __restrict__ x,
                               const float* __restrict__ wq, const float* __restrict__ wk,
                               const float* __restrict__ wv, const float* __restrict__ wo,
                               unsigned short* __restrict__ xb, unsigned short* __restrict__ wb) {
#pragma unroll
    for (int it = 0; it < 4; it++) {
        int gid = blockIdx.x * blockDim.x + threadIdx.x + it * (2048 * 256);
        long i4 = (long)gid * 4;
        const float* src;
        unsigned short* dst;
        long off;
        if (i4 < (long)kBS * kD) {
            src = x; dst = xb; off = i4;
        } else {
            long w = i4 - (long)kBS * kD;
            int sel = (int)(w >> 20);
            off = w & 1048575;
            src = (sel == 0) ? wq : (sel == 1) ? wk : (sel == 2) ? wv : wo;
            dst = wb + (long)sel * 1048576;
        }
        float4 v = *(const float4*)(src + off);
        ushort4 o;
        o.x = f2b(v.x); o.y = f2b(v.y); o.z = f2b(v.z); o.w = f2b(v.w);
        *(ushort4*)(dst + off) = o;
    }
}

// ---------------------------------------------------------------------------
// K1: NT GEMM  C[M,N] = A[M,K] @ B[N,K]^T   (bf16 in, fp32 accum)
// BK=64: 32 MFMAs per barrier-pair. Staging via global_load_lds w=16 with
// 8-chunk XOR swizzle; 32 KB LDS. __launch_bounds__(256,3): 768 blocks fit
// one resident generation (3 blocks/CU). Body bit-exact since r0.
// MODE 0 only now: bf16 C; z==0 (Q) scaled by 0.125*log2(e) (exp2 domain).
// ---------------------------------------------------------------------------
template <int MODE>
__launch_bounds__(256, 3)
__global__ void gemm_nt(const unsigned short* __restrict__ A,
                        const unsigned short* __restrict__ Bw,
                        void* __restrict__ Cout,
                        const float* __restrict__ resid,
                        int M, int N, int K) {
    __shared__ __align__(16) unsigned short As[128 * 64];
    __shared__ __align__(16) unsigned short Bs[128 * 64];

    const int z  = blockIdx.z;
    const unsigned short* Bp = Bw + (size_t)z * N * K;
    const int m0 = blockIdx.y * 128, n0 = blockIdx.x * 128;
    const int tid  = threadIdx.x;
    const int lane = tid & 63, wv = tid >> 6;
    const int wm = wv >> 1, wn = wv & 1;
    const int quad = lane >> 4, l16 = lane & 15;

    floatx4 acc[4][4] = {};

    const int r0 = lane >> 3;
    const int jc = ((lane & 7) ^ r0) * 8;
    const unsigned short* Ag[4];
    const unsigned short* Bg[4];
    unsigned short* Asd[4];
    unsigned short* Bsd[4];
#pragma unroll
    for (int seg = 0; seg < 4; seg++) {
        const int row = seg * 32 + wv * 8 + r0;        // 0..127
        Ag[seg] = A  + (size_t)(m0 + row) * K + jc;    // + k0 per iter
        Bg[seg] = Bp + (size_t)(n0 + row) * K + jc;
        Asd[seg] = As + (seg * 32 + wv * 8) * 64;      // wave-uniform
        Bsd[seg] = Bs + (seg * 32 + wv * 8) * 64;
    }

    const int pk0 = (quad ^ (l16 & 7)) * 8;
    const int pk1 = ((4 + quad) ^ (l16 & 7)) * 8;

    for (int k0 = 0; k0 < K; k0 += 64) {
        __syncthreads();
#pragma unroll
        for (int seg = 0; seg < 4; seg++) {
            gload16(Ag[seg] + k0, Asd[seg]);
            gload16(Bg[seg] + k0, Bsd[seg]);
        }
        __syncthreads();

#pragma unroll
        for (int h = 0; h < 2; h++) {
            const int pk = h ? pk1 : pk0;
            short8 af[4], bf[4];
#pragma unroll
            for (int i = 0; i < 4; i++)
                af[i] = *(const short8*)(As + (wm * 64 + i * 16 + l16) * 64 + pk);
#pragma unroll
            for (int j = 0; j < 4; j++)
                bf[j] = *(const short8*)(Bs + (wn * 64 + j * 16 + l16) * 64 + pk);
#pragma unroll
            for (int i = 0; i < 4; i++)
#pragma unroll
                for (int j = 0; j < 4; j++)
                    acc[i][j] = mfma16(af[i], bf[j], acc[i][j]);
        }
    }

#pragma unroll
    for (int i = 0; i < 4; i++)
#pragma unroll
        for (int j = 0; j < 4; j++) {
            const int row = m0 + wm * 64 + i * 16 + quad * 4;
            const int col = n0 + wn * 64 + j * 16 + l16;
#pragma unroll
            for (int r = 0; r < 4; r++) {
                float v = acc[i][j][r];
                if (MODE == 0) {
                    if (z == 0) v *= 0.18033688f;   // 0.125 * log2(e)
                    ((unsigned short*)Cout)[(size_t)z * M * N + (size_t)(row + r) * N + col] = f2b(v);
                } else {
                    size_t idx = (size_t)(row + r) * N + col;
                    ((float*)Cout)[idx] = v + resid[idx];
                }
            }
        }
}

// ---------------------------------------------------------------------------
// K1b: output-projection GEMM + residual — round 12: 64x128 tile.
// The old MODE-1 grid was 256 blocks = 1 block/CU = 1 wave/SIMD (worst
// latency hiding on the chip). M-split to 64-row tiles -> 512 blocks,
// 2-3 blocks/CU. Per-output K-accumulation chain (fragment mapping, h/pk/k0
// order) is UNCHANGED -> bit-exact vs the old MODE-1 kernel. LDS 24 KB.
// ---------------------------------------------------------------------------
__launch_bounds__(256, 3)
__global__ void gemm_nt1(const unsigned short* __restrict__ A,
                         const unsigned short* __restrict__ Bw,
                         float* __restrict__ Cout,
                         const float* __restrict__ resid,
                         int M, int N, int K) {
    __shared__ __align__(16) unsigned short As[64 * 64];
    __shared__ __align__(16) unsigned short Bs[128 * 64];

    const int m0 = blockIdx.y * 64, n0 = blockIdx.x * 128;
    const int tid  = threadIdx.x;
    const int lane = tid & 63, wv = tid >> 6;
    const int wm = wv >> 1, wn = wv & 1;
    const int quad = lane >> 4, l16 = lane & 15;

    floatx4 acc[2][4] = {};

    const int r0 = lane >> 3;
    const int jc = ((lane & 7) ^ r0) * 8;
    const unsigned short* Ag[2];
    const unsigned short* Bg[4];
    unsigned short* Asd[2];
    unsigned short* Bsd[4];
#pragma unroll
    for (int seg = 0; seg < 2; seg++) {
        const int row = seg * 32 + wv * 8 + r0;        // 0..63
        Ag[seg]  = A + (size_t)(m0 + row) * K + jc;    // + k0 per iter
        Asd[seg] = As + (seg * 32 + wv * 8) * 64;      // wave-uniform
    }
#pragma unroll
    for (int seg = 0; seg < 4; seg++) {
        const int row = seg * 32 + wv * 8 + r0;        // 0..127
        Bg[seg]  = Bw + (size_t)(n0 + row) * K + jc;
        Bsd[seg] = Bs + (seg * 32 + wv * 8) * 64;
    }

    const int pk0 = (quad ^ (l16 & 7)) * 8;
    const int pk1 = ((4 + quad) ^ (l16 & 7)) * 8;

    for (int k0 = 0; k0 < K; k0 += 64) {
        __syncthreads();
#pragma unroll
        for (int seg = 0; seg < 2; seg++)
            gload16(Ag[seg] + k0, Asd[seg]);
#pragma unroll
        for (int seg = 0; seg < 4; seg++)
            gload16(Bg[seg] + k0, Bsd[seg]);
        __syncthreads();

#pragma unroll
        for (int h = 0; h < 2; h++) {
            const int pk = h ? pk1 : pk0;
            short8 af[2], bf[4];
#pragma unroll
            for (int i = 0; i < 2; i++)
                af[i] = *(const short8*)(As + (wm * 32 + i * 16 + l16) * 64 + pk);
#pragma unroll
            for (int j = 0; j < 4; j++)
                bf[j] = *(const short8*)(Bs + (wn * 64 + j * 16 + l16) * 64 + pk);
#pragma unroll
            for (int i = 0; i < 2; i++)
#pragma unroll
                for (int j = 0; j < 4; j++)
                    acc[i][j] = mfma16(af[i], bf[j], acc[i][j]);
        }
    }

#pragma unroll
    for (int i = 0; i < 2; i++)
#pragma unroll
        for (int j = 0; j < 4; j++) {
            const int row = m0 + wm * 32 + i * 16 + quad * 4;
            const int col = n0 + wn * 64 + j * 16 + l16;
#pragma unroll
            for (int r = 0; r < 4; r++) {
                size_t idx = (size_t)(row + r) * N + col;
                Cout[idx] = acc[i][j][r] + resid[idx];
            }
        }
}

// ---------------------------------------------------------------------------
// K2: FUSED column-softmax denominators + scaled V^T — key-split (64 keys/
// block, grid 1024, 4 blocks/CU) + tile-pair interleave (r11-verified).
// Phase 1: invl[k] = 1/sum_q exp2(s[q,k]) (K-stationary).
// Phase 2: VT[bh][d][k] = V[b][k][h*64+d] * invl[k].
// ---------------------------------------------------------------------------
__launch_bounds__(256, 4)
__global__ void stats_vt_kernel(const unsigned short* __restrict__ Qb,
                                const unsigned short* __restrict__ Kb,
                                const unsigned short* __restrict__ Vb,
                                unsigned short* __restrict__ VT) {
    // two staging tiles; Qs[0] reused as the 64x65 transpose tile in phase 2
    __shared__ __align__(16) unsigned short Qs[2][64 * 66];
    __shared__ float s_inv[64];

    const int id = blockIdx.x;                       // 0..1023
    const int bh = (id & 7) + 8 * ((id >> 3) & 3);   // XCD-grouped
    const int keyblk = id >> 5;                      // 0..31 (64 keys each)
    const int b = bh >> 4, h = bh & 15;
    const int tid = threadIdx.x, lane = tid & 63, w = tid >> 6;   // w = 0..3
    const int quad = lane >> 4, l16 = lane & 15;
    const int keybase = keyblk * 64 + w * 16;        // 16 keys per wave

    // A-frag: K rows (one 16-key tile x 2 dh-halves), held in regs
    short8 ak0, ak1;
    {
        const unsigned short* Krow = Kb + (size_t)(b * kS + keybase + l16) * kD + h * kDh;
        ak0 = *(const short8*)(Krow + quad * 8);
        ak1 = *(const short8*)(Krow + 32 + quad * 8);
    }

    // staging: wave w covers rows w*16 .. w*16+15 (2 segs of 8 rows);
    // lane covers row seg*8 + (lane>>3), logical 16B chunk (lane&7)^r0
    const int r0 = lane >> 3;
    const int jc = ((lane & 7) ^ r0) * 8;
    const unsigned short* Qg[2];
    int loff[2];
#pragma unroll
    for (int seg = 0; seg < 2; seg++) {
        const int row = w * 16 + seg * 8 + r0;              // 0..63
        Qg[seg] = Qb + (size_t)(b * kS + row) * kD + h * kDh + jc;   // + q0*kD per chunk
        loff[seg] = (w * 16 + seg * 8) * 64;                // wave-uniform
    }

    const int pk0 = (quad ^ (l16 & 7)) * 8;
    const int pk1 = ((4 + quad) ^ (l16 & 7)) * 8;

    float lacc[4] = {};

    for (int q0 = 0; q0 < kS; q0 += 128) {
        __syncthreads();   // previous tiles' reads complete before overwrite
#pragma unroll
        for (int seg = 0; seg < 2; seg++) {
            gload16(Qg[seg] + (size_t)q0 * kD,        &Qs[0][loff[seg]]);
            gload16(Qg[seg] + (size_t)(q0 + 64) * kD, &Qs[1][loff[seg]]);
        }
        __syncthreads();   // implicit vmcnt(0): both tiles landed

#pragma unroll
        for (int tb = 0; tb < 2; tb++) {
#pragma unroll
            for (int c = 0; c < 4; c++) {
                const unsigned short* row = &Qs[tb][(c * 16 + l16) * 64];
                short8 bq0 = *(const short8*)(row + pk0);
                short8 bq1 = *(const short8*)(row + pk1);
                floatx4 t = {0.f, 0.f, 0.f, 0.f};
                t = mfma16(ak0, bq0, t);
                t = mfma16(ak1, bq1, t);
#pragma unroll
                for (int r = 0; r < 4; r++)
                    lacc[r] += exp2f(t[r]);
            }
        }
    }

    // reduce across the 16 l16 lanes (q columns) within each quad
#pragma unroll
    for (int off = 1; off <= 8; off <<= 1)
#pragma unroll
        for (int r = 0; r < 4; r++)
            lacc[r] += __shfl_xor(lacc[r], off, 64);

    __syncthreads();   // Qs reads done before tile reuse; also orders s_inv
    if (l16 == 0) {
#pragma unroll
        for (int r = 0; r < 4; r++)
            s_inv[w * 16 + quad * 4 + r] = 1.0f / lacc[r];
    }
    __syncthreads();

    // Phase 2: scaled V^T for this block's 64 keys.
    unsigned short* tile = &Qs[0][0];   // reuse, stride 65 (4160 <= 4224 OK)
    {
        const int kr = tid >> 2, dc = (tid & 3) * 16;
        const float iv = s_inv[kr];
        const unsigned short* src =
            Vb + (size_t)(b * kS + keyblk * 64 + kr) * kD + h * kDh + dc;
        unsigned short vs[16];
        *(uint4*)(vs)     = *(const uint4*)(src);
        *(uint4*)(vs + 8) = *(const uint4*)(src + 8);
#pragma unroll
        for (int i = 0; i < 16; i++)
            tile[kr * 65 + dc + i] = f2b(b2f(vs[i]) * iv);
    }
    __syncthreads();
    {
        const int d = tid >> 2, kc = (tid & 3) * 16;
        unsigned short os[16];
#pragma unroll
        for (int j = 0; j < 16; j++) os[j] = tile[(kc + j) * 65 + d];
        unsigned short* dst =
            VT + (size_t)bh * kDh * kS + (size_t)d * kS + keyblk * 64 + kc;
        *(uint4*)(dst)     = *(uint4*)(os);
        *(uint4*)(dst + 8) = *(uint4*)(os + 8);
    }
}

// ---------------------------------------------------------------------------
// K3: ctx = exp2(S) @ VT^T — tile-pair interleave (verified r9/r11, absmax
// 0.03125). FROZEN: latency floor at 2 waves/SIMD; all further levers
// change accumulation order (fatal, round 4). Same-source noise band
// 61.6-68.3us; do not chase.
// ---------------------------------------------------------------------------
__launch_bounds__(256, 2)
__global__ void ctx_kernel(const unsigned short* __restrict__ Qb,
                           const unsigned short* __restrict__ Kb,
                           const unsigned short* __restrict__ VT,
                           unsigned short* __restrict__ Ctx) {
    // [tile][0] = K tile, [tile][1] = VT tile; 32 KB total.
    __shared__ __align__(16) unsigned short Sh[2][2][64 * 64];

    const int id = blockIdx.x;                       // 0..511
    const int bh = (id & 7) + 8 * ((id >> 3) & 3);   // XCD-grouped
    const int qblk = id >> 5;                        // 0..15
    const int b = bh >> 4, h = bh & 15;
    const int tid = threadIdx.x, lane = tid & 63, w = tid >> 6;   // w = 0..3
    const int l32 = lane & 31, hi = lane >> 5;
    const int qbase = qblk * 128 + w * 32;           // 32 q per wave

    // Q-frags (B-operand of QK^T), 4 dh-ksteps: lane: q=l32, dh=kq*16+hi*8
    short8 aq[4];
    {
        const unsigned short* Qrow =
            Qb + (size_t)(b * kS + qbase + l32) * kD + h * kDh + hi * 8;
#pragma unroll
        for (int kq = 0; kq < 4; kq++)
            aq[kq] = *(const short8*)(Qrow + kq * 16);
    }
    floatx16 acc[2] = {};   // PV acc: d-tiles t=0,1 (rows=q via regs, col=lane&31=d)

    const unsigned short* Kbase = Kb + (size_t)(b * kS) * kD + h * kDh;
    const unsigned short* VTb   = VT + (size_t)bh * kDh * kS;

    // staging: 4 waves cover 64 rows, XOR-chunk source (linear LDS dest)
    const int r0 = lane >> 3;
    const int jc = ((lane & 7) ^ r0) * 8;
    const unsigned short* Kg[2];
    const unsigned short* Vg[2];
    int loff[2];
#pragma unroll
    for (int seg = 0; seg < 2; seg++) {
        const int row = w * 16 + seg * 8 + r0;         // 0..63
        Kg[seg] = Kbase + (size_t)row * kD + jc;       // + k0*kD per chunk
        Vg[seg] = VTb + (size_t)row * kS + jc;         // + k0 per chunk
        loff[seg] = (w * 16 + seg * 8) * 64;           // wave-uniform
    }

    const int x7 = l32 & 7;    // row&7 for the chunk swizzle

    for (int k0 = 0; k0 < kS; k0 += 128) {
        // stage tile k0 into Sh[0], tile k0+64 into Sh[1]
#pragma unroll
        for (int seg = 0; seg < 2; seg++) {
            gload16(Kg[seg] + (size_t)k0 * kD,        &Sh[0][0][loff[seg]]);
            gload16(Vg[seg] + k0,                     &Sh[0][1][loff[seg]]);
            gload16(Kg[seg] + (size_t)(k0 + 64) * kD, &Sh[1][0][loff[seg]]);
            gload16(Vg[seg] + (k0 + 64),              &Sh[1][1][loff[seg]]);
        }
        __syncthreads();   // implicit vmcnt(0): both tiles landed

        // two round-3-verbatim compute bodies, no barrier between ->
        // compiler can interleave tile1's ds_read/QK^T with tile0's
        // exp2/pack/PV. Accumulation order preserved (tb=0 then tb=1).
#pragma unroll
        for (int tb = 0; tb < 2; tb++) {
            const unsigned short* Ks  = Sh[tb][0];
            const unsigned short* VTs = Sh[tb][1];

            // QK^T: sc[s] = K-tile(s) x Q -> D[key][q], col=lane&31=q,
            // key = (r&3) + 8*(r>>2) + 4*hi (+32s)
            floatx16 sc[2];
#pragma unroll
            for (int s = 0; s < 2; s++) {
                const unsigned short* arow = Ks + (s * 32 + l32) * 64;
                floatx16 t = {0.f,0.f,0.f,0.f,0.f,0.f,0.f,0.f,
                              0.f,0.f,0.f,0.f,0.f,0.f,0.f,0.f};
#pragma unroll
                for (int kq = 0; kq < 4; kq++) {
                    short8 af = *(const short8*)(arow + ((2 * kq + hi) ^ x7) * 8);
                    t = mfma32(af, aq[kq], t);
                }
                sc[s] = t;
            }

            // P build fully in-register: exp2 -> truncating bf16 pack ->
            // permlane32_swap. pa[kk] = A-frag (q=l32, keys kk*16+hi*8..+8).
            short8 pa[4];
#pragma unroll
            for (int s = 0; s < 2; s++) {
                float e[16];
#pragma unroll
                for (int r = 0; r < 16; r++) e[r] = exp2f(sc[s][r]);
                unsigned p0 = packbf(e[0],  e[1]),  p1 = packbf(e[2],  e[3]);
                unsigned p2 = packbf(e[4],  e[5]),  p3 = packbf(e[6],  e[7]);
                unsigned p4 = packbf(e[8],  e[9]),  p5 = packbf(e[10], e[11]);
                unsigned p6 = packbf(e[12], e[13]), p7 = packbf(e[14], e[15]);
                asm volatile("v_permlane32_swap_b32 %0, %1" : "+v"(p0), "+v"(p2));
                asm volatile("v_permlane32_swap_b32 %0, %1" : "+v"(p1), "+v"(p3));
                asm volatile("v_permlane32_swap_b32 %0, %1" : "+v"(p4), "+v"(p6));
                asm volatile("v_permlane32_swap_b32 %0, %1" : "+v"(p5), "+v"(p7));
                union { unsigned u[4]; short8 v; } f0, f1;
                f0.u[0] = p0; f0.u[1] = p1; f0.u[2] = p2; f0.u[3] = p3;
                f1.u[0] = p4; f1.u[1] = p5; f1.u[2] = p6; f1.u[3] = p7;
                pa[2 * s]     = f0.v;
                pa[2 * s + 1] = f1.v;
            }

            // PV: acc[t] += P x VT-tile(t) -> D[q][d]
#pragma unroll
            for (int t = 0; t < 2; t++) {
                const unsigned short* brow = VTs + (t * 32 + l32) * 64;
#pragma unroll
                for (int kk = 0; kk < 4; kk++) {
                    short8 bv = *(const short8*)(brow + ((2 * kk + hi) ^ x7) * 8);
                    acc[t] = mfma32(pa[kk], bv, acc[t]);
                }
            }
        }

        __syncthreads();   // all reads done before next stage overwrites
    }

    // D layout: col=lane&31 = d_local (within tile t), row q = (r&3)+8*(r>>2)+4*hi
#pragma unroll
    for (int t = 0; t < 2; t++)
#pragma unroll
        for (int rg = 0; rg < 4; rg++)
#pragma unroll
            for (int j = 0; j < 4; j++) {
                const int q = qbase + rg * 8 + hi * 4 + j;
                const int d = h * kDh + t * 32 + l32;
                Ctx[(size_t)(b * kS + q) * kD + d] = f2b(acc[t][rg * 4 + j]);
            }
}

// ---------------------------------------------------------------------------
// K4: row LayerNorm — round 12: wave-per-row, ZERO barriers.
// Old: 4096 one-row blocks, 2 __syncthreads + LDS handoff each. New: 1024
// blocks x 4 waves; each wave owns a row (16 floats/lane), shfl tree +
// lane-0 broadcast. Reduction regrouping is fp32-level (<=1e-4 on mu/sigma)
// — invisible at the 0.03 absmax scale (bf16-path dominated).
// ---------------------------------------------------------------------------
__global__ void ln_kernel(const float* __restrict__ R, const float* __restrict__ gamma,
                          const float* __restrict__ beta, float* __restrict__ out) {
    const int tid = threadIdx.x, lane = tid & 63, w = tid >> 6;
    const int row = blockIdx.x * 4 + w;
    const float* Rr = R + (size_t)row * kD;
    float4 v[4];
    float s = 0.f, ss = 0.f;
#pragma unroll
    for (int c = 0; c < 4; c++) {
        v[c] = ((const float4*)Rr)[lane + 64 * c];
        s  += v[c].x + v[c].y + v[c].z + v[c].w;
        ss += v[c].x * v[c].x + v[c].y * v[c].y + v[c].z * v[c].z + v[c].w * v[c].w;
    }
#pragma unroll
    for (int off = 32; off > 0; off >>= 1) {
        s  += __shfl_down(s, off, 64);
        ss += __shfl_down(ss, off, 64);
    }
    const float S1 = __shfl(s, 0, 64);
    const float S2 = __shfl(ss, 0, 64);
    const float mu  = S1 * (1.0f / kD);
    const float inv = rsqrtf(S2 * (1.0f / kD) - mu * mu + 1e-5f);
    float* Or = out + (size_t)row * kD;
#pragma unroll
    for (int c = 0; c < 4; c++) {
        const float4 g  = ((const float4*)gamma)[lane + 64 * c];
        const float4 bb = ((const float4*)beta)[lane + 64 * c];
        float4 o;
        o.x = (v[c].x - mu) * inv * g.x + bb.x;
        o.y = (v[c].y - mu) * inv * g.y + bb.y;
        o.z = (v[c].z - mu) * inv * g.z + bb.z;
        o.w = (v[c].w - mu) * inv * g.w + bb.w;
        ((float4*)Or)[lane + 64 * c] = o;
    }
}

// ---------------------------------------------------------------------------
// Workspace layout (64 MB peak, aliasing is stream-ordered-safe):
//   [0,   8MB)  Xb bf16
//   [8,  16MB)  Wb bf16 wq|wk|wv|wo
//   [16, 40MB)  QKV bf16 Q|K|V  (Q pre-scaled by 0.125*log2e)
//   [40, 48MB)  Ctx bf16
//   [48, 64MB)  VT bf16 [32][64][2048]; ALIASES R (written strictly later)
// ---------------------------------------------------------------------------
extern "C" void kernel_launch(void* const* d_in, const int* in_sizes, int n_in,
                              void* d_out, int out_size, void* d_ws, size_t ws_size,
                              hipStream_t stream) {
    const float* x     = (const float*)d_in[0];
    const float* wq    = (const float*)d_in[1];
    const float* wk    = (const float*)d_in[2];
    const float* wv    = (const float*)d_in[3];
    const float* wo    = (const float*)d_in[4];
    const float* gamma = (const float*)d_in[5];
    const float* beta  = (const float*)d_in[6];
    float* out = (float*)d_out;

    char* ws = (char*)d_ws;
    unsigned short* Xb  = (unsigned short*)(ws);
    unsigned short* Wb  = (unsigned short*)(ws + (8u  << 20));
    unsigned short* QKV = (unsigned short*)(ws + (16u << 20));
    unsigned short* Qb  = QKV;
    unsigned short* Kb  = QKV + (size_t)kBS * kD;
    unsigned short* Vb  = QKV + (size_t)2 * kBS * kD;
    unsigned short* Ctx = (unsigned short*)(ws + (40u << 20));
    unsigned short* VT  = (unsigned short*)(ws + (48u << 20));
    float* R            = (float*)(ws + (48u << 20));  // aliases VT

    convert_kernel<<<2048, 256, 0, stream>>>(x, wq, wk, wv, wo, Xb, Wb);

    gemm_nt<0><<<dim3(kD / 128, kBS / 128, 3), 256, 0, stream>>>(
        Xb, Wb, QKV, nullptr, kBS, kD, kD);

    stats_vt_kernel<<<1024, 256, 0, stream>>>(Qb, Kb, Vb, VT);

    ctx_kernel<<<512, 256, 0, stream>>>(Qb, Kb, VT, Ctx);

    gemm_nt1<<<dim3(kD / 128, kBS / 64, 1), 256, 0, stream>>>(
        Ctx, Wb + (size_t)3 * kD * kD, R, x, kBS, kD, kD);

    ln_kernel<<<kBS / 4, 256, 0, stream>>>(R, gamma, beta, out);
}